// Round 8
// baseline (229.863 us; speedup 1.0000x reference)
//
#include <hip/hip_runtime.h>
#include <math.h>

#define EMBED 768
#define DI 1536
#define DSTATE 16
#define DCONV 4
#define DTRANK 48
#define FF 3072
#define BATCH 2
#define SEQ 1024
#define NROWS (BATCH*SEQ)
#define TCH 32
#define NCH (SEQ/TCH)
#define DBLK 64

typedef __bf16 bf16x8 __attribute__((ext_vector_type(8)));
typedef float f32x4 __attribute__((ext_vector_type(4)));
typedef unsigned int u32x4 __attribute__((ext_vector_type(4)));

static __device__ __forceinline__ unsigned short f2b(float f) {
    union { float f; unsigned u; } v; v.f = f;
    unsigned r = v.u + 0x7FFFu + ((v.u >> 16) & 1u);
    return (unsigned short)(r >> 16);
}
static __device__ __forceinline__ float b2f(unsigned short s) {
    union { unsigned u; float f; } v; v.u = ((unsigned)s) << 16;
    return v.f;
}

#define GLOAD_LDS16(g, l) __builtin_amdgcn_global_load_lds( \
    (const __attribute__((address_space(1))) void*)(g), \
    (__attribute__((address_space(3))) void*)(l), 16, 0, 0)

// ---------------------------------------------------------------------------
// gemm_b: C[M,N] = A[M,K](bf16) @ W[N,K](bf16)^T, 128x128 tile, BK=32.
// global_load_lds staging, XOR swizzle on source col + ds_read offset.
// 4 waves, each owns 64x64 (4x4 frags of 16x16x32). KSPLIT>1 -> f32 partials.
// EPI: 1 softplus(acc+bias)->C ; 3 gelu(acc+bias)->Cb(bf16) ;
//      5 split col<DI -> C f32 (stride DI), else Cb bf16
// ---------------------------------------------------------------------------
template<int EPI, int KSPLIT>
__global__ __launch_bounds__(256)
void gemm_b(const unsigned short* __restrict__ A,
            const unsigned short* __restrict__ W,
            float* __restrict__ C, unsigned short* __restrict__ Cb,
            float* __restrict__ part,
            int M, int N, int K,
            const float* __restrict__ bias)
{
    __shared__ alignas(16) unsigned short As[128 * 32];   // 8 KB
    __shared__ alignas(16) unsigned short Ws[128 * 32];   // 8 KB
    const int tid  = threadIdx.x;
    const int lane = tid & 63, wave = tid >> 6;
    const int wr = (wave >> 1) * 64, wc = (wave & 1) * 64;
    const int bm = blockIdx.y * 128, bn = blockIdx.x * 128;
    const int kc = K / KSPLIT;
    const int kz = blockIdx.z * kc;
    const int ln = lane & 15, lg = lane >> 4;

    f32x4 acc[4][4];
    #pragma unroll
    for (int i = 0; i < 4; ++i)
        #pragma unroll
        for (int j = 0; j < 4; ++j)
            acc[i][j] = (f32x4){0.f, 0.f, 0.f, 0.f};

    // staging: thread -> row ra=tid>>2, 16B-unit ca=tid&3, source col swizzled
    const int ra = tid >> 2, ca = tid & 3;
    const int cs = (ca * 8) ^ ((ra & 3) << 3);
    const unsigned short* gA0 = A + (size_t)(bm + ra) * K + kz + cs;
    const unsigned short* gA1 = A + (size_t)(bm + ra + 64) * K + kz + cs;
    const unsigned short* gW0 = W + (size_t)(bn + ra) * K + kz + cs;
    const unsigned short* gW1 = W + (size_t)(bn + ra + 64) * K + kz + cs;
    unsigned short* ldsA0 = As + wave * 512;
    unsigned short* ldsA1 = As + 2048 + wave * 512;
    unsigned short* ldsW0 = Ws + wave * 512;
    unsigned short* ldsW1 = Ws + 2048 + wave * 512;

    for (int k0 = 0; k0 < kc; k0 += 32) {
        GLOAD_LDS16(gA0 + k0, ldsA0);
        GLOAD_LDS16(gA1 + k0, ldsA1);
        GLOAD_LDS16(gW0 + k0, ldsW0);
        GLOAD_LDS16(gW1 + k0, ldsW1);
        __syncthreads();
        bf16x8 af[4], wf[4];
        #pragma unroll
        for (int i = 0; i < 4; ++i) {
            int row = wr + i * 16 + ln;
            af[i] = *reinterpret_cast<const bf16x8*>(
                &As[row * 32 + ((lg * 8) ^ ((row & 3) << 3))]);
        }
        #pragma unroll
        for (int j = 0; j < 4; ++j) {
            int row = wc + j * 16 + ln;
            wf[j] = *reinterpret_cast<const bf16x8*>(
                &Ws[row * 32 + ((lg * 8) ^ ((row & 3) << 3))]);
        }
        #pragma unroll
        for (int i = 0; i < 4; ++i)
            #pragma unroll
            for (int j = 0; j < 4; ++j)
                acc[i][j] = __builtin_amdgcn_mfma_f32_16x16x32_bf16(af[i], wf[j], acc[i][j], 0, 0, 0);
        __syncthreads();
    }

    if constexpr (KSPLIT > 1) {
        float* pb = part + (size_t)blockIdx.z * M * N;
        #pragma unroll
        for (int i = 0; i < 4; ++i)
            #pragma unroll
            for (int j = 0; j < 4; ++j) {
                int col = bn + wc + j * 16 + ln;
                #pragma unroll
                for (int rr = 0; rr < 4; ++rr) {
                    int row = bm + wr + i * 16 + lg * 4 + rr;
                    pb[(size_t)row * N + col] = acc[i][j][rr];
                }
            }
    } else {
        #pragma unroll
        for (int i = 0; i < 4; ++i)
            #pragma unroll
            for (int j = 0; j < 4; ++j) {
                int col = bn + wc + j * 16 + ln;
                #pragma unroll
                for (int rr = 0; rr < 4; ++rr) {
                    int row = bm + wr + i * 16 + lg * 4 + rr;
                    float v = acc[i][j][rr];
                    size_t o = (size_t)row * N + col;
                    if (EPI == 1) {
                        v += bias[col];
                        C[o] = (v > 20.f) ? v : log1pf(expf(v));
                    } else if (EPI == 3) {
                        v += bias[col];
                        float t = 0.7978845608028654f * (v + 0.044715f * v * v * v);
                        Cb[o] = f2b(0.5f * v * (1.f + tanhf(t)));
                    } else if (EPI == 5) {
                        if (col < DI) C[(size_t)row * DI + col] = v;
                        else          Cb[(size_t)row * DI + col - DI] = f2b(v);
                    } else {
                        C[o] = v;
                    }
                }
            }
    }
}

// ---------------------------------------------------------------------------
// reduce_ln: sum KS split-K partials (+bias) (+resid), then LayerNorm(768).
// One block per row. out f32 (+ optional bf16 copy).
// ---------------------------------------------------------------------------
template<int KS, int BIAS>
__global__ __launch_bounds__(256)
void reduce_ln(const float* __restrict__ part, const float* __restrict__ resid,
               const float* __restrict__ bias,
               const float* __restrict__ w, const float* __restrict__ bb,
               float* __restrict__ out, unsigned short* __restrict__ outb)
{
    const int row = blockIdx.x;
    const size_t ro = (size_t)row * EMBED;
    const int i0 = threadIdx.x, i1 = i0 + 256, i2 = i0 + 512;
    float v0 = 0.f, v1 = 0.f, v2 = 0.f;
    #pragma unroll
    for (int z = 0; z < KS; ++z) {
        const float* p = part + (size_t)z * NROWS * EMBED + ro;
        v0 += p[i0]; v1 += p[i1]; v2 += p[i2];
    }
    if (BIAS) { v0 += bias[i0]; v1 += bias[i1]; v2 += bias[i2]; }
    v0 += resid[ro + i0]; v1 += resid[ro + i1]; v2 += resid[ro + i2];

    float s  = v0 + v1 + v2;
    float s2 = v0 * v0 + v1 * v1 + v2 * v2;
    #pragma unroll
    for (int m = 1; m < 64; m <<= 1) {
        s  += __shfl_xor(s,  m);
        s2 += __shfl_xor(s2, m);
    }
    __shared__ float sh1[4], sh2[4];
    int wv = threadIdx.x >> 6;
    if ((threadIdx.x & 63) == 0) { sh1[wv] = s; sh2[wv] = s2; }
    __syncthreads();
    float S1 = sh1[0] + sh1[1] + sh1[2] + sh1[3];
    float S2 = sh2[0] + sh2[1] + sh2[2] + sh2[3];
    float mu  = S1 * (1.f / EMBED);
    float var = S2 * (1.f / EMBED) - mu * mu;
    float rs  = rsqrtf(var + 1e-5f);
    float o0 = (v0 - mu) * rs * w[i0] + bb[i0];
    float o1 = (v1 - mu) * rs * w[i1] + bb[i1];
    float o2 = (v2 - mu) * rs * w[i2] + bb[i2];
    out[ro + i0] = o0; out[ro + i1] = o1; out[ro + i2] = o2;
    if (outb) {
        outb[ro + i0] = f2b(o0); outb[ro + i1] = f2b(o1); outb[ro + i2] = f2b(o2);
    }
}

// ---------------------------------------------------------------------------
// x_proj split-K MFMA + reduce
// ---------------------------------------------------------------------------
__global__ __launch_bounds__(256)
void xproj_mfma(const unsigned short* __restrict__ A,
                const unsigned short* __restrict__ W,
                float* __restrict__ part)
{
    const int mt = blockIdx.x, s = blockIdx.y;
    const int lane = threadIdx.x & 63, wave = threadIdx.x >> 6;
    const int ln = lane & 15, lg = lane >> 4;
    const int row0 = mt * 128 + wave * 32;
    const int kb = s * 192;
    f32x4 acc[2][5];
    #pragma unroll
    for (int i = 0; i < 2; ++i)
        #pragma unroll
        for (int j = 0; j < 5; ++j)
            acc[i][j] = (f32x4){0.f, 0.f, 0.f, 0.f};

    for (int kk = 0; kk < 192; kk += 32) {
        const int k = kb + kk + lg * 8;
        bf16x8 af[2], wf[5];
        af[0] = *reinterpret_cast<const bf16x8*>(A + (size_t)(row0 + ln) * DI + k);
        af[1] = *reinterpret_cast<const bf16x8*>(A + (size_t)(row0 + 16 + ln) * DI + k);
        #pragma unroll
        for (int j = 0; j < 5; ++j)
            wf[j] = *reinterpret_cast<const bf16x8*>(W + (size_t)(j * 16 + ln) * DI + k);
        #pragma unroll
        for (int i = 0; i < 2; ++i)
            #pragma unroll
            for (int j = 0; j < 5; ++j)
                acc[i][j] = __builtin_amdgcn_mfma_f32_16x16x32_bf16(af[i], wf[j], acc[i][j], 0, 0, 0);
    }
    float* pb = part + (size_t)s * NROWS * 80;
    #pragma unroll
    for (int i = 0; i < 2; ++i)
        #pragma unroll
        for (int j = 0; j < 5; ++j)
            #pragma unroll
            for (int rr = 0; rr < 4; ++rr) {
                int row = row0 + i * 16 + lg * 4 + rr;
                int col = j * 16 + ln;
                pb[(size_t)row * 80 + col] = acc[i][j][rr];
            }
}

__global__ __launch_bounds__(256)
void xproj_reduce(const float* __restrict__ part, float* __restrict__ xdbl,
                  unsigned short* __restrict__ xdblb)
{
    int idx = blockIdx.x * 256 + threadIdx.x;      // 163840
    float sum = 0.f;
    #pragma unroll
    for (int s = 0; s < 8; ++s) sum += part[(size_t)s * NROWS * 80 + idx];
    xdbl[idx] = sum;
    int col = idx % 80, row = idx / 80;
    if (col < 48)      xdblb[row * 64 + col] = f2b(sum);
    else if (col < 64) xdblb[row * 64 + col] = 0;
}

// ---------------------------------------------------------------------------
// f32 -> bf16 conversion: x + 4 big weights + x_proj_w + padded dt_proj_w.
// ---------------------------------------------------------------------------
__global__ __launch_bounds__(256)
void cvt7_k(const float* __restrict__ x,  const float* __restrict__ w1,
            const float* __restrict__ w2, const float* __restrict__ w3,
            const float* __restrict__ w4, const float* __restrict__ w5,
            const float* __restrict__ w6,
            unsigned short* __restrict__ xb,  unsigned short* __restrict__ w1b,
            unsigned short* __restrict__ w2b, unsigned short* __restrict__ w3b,
            unsigned short* __restrict__ w4b, unsigned short* __restrict__ w5b,
            unsigned short* __restrict__ w6b)
{
    size_t i4 = ((size_t)blockIdx.x * 256 + threadIdx.x) * 4;
    if (i4 >= 9953280u) {
        // dt_proj_w [1536][48] -> [1536][64] padded
        int off = (int)(i4 - 9953280u);
        if (off >= 98304) return;
        int row = off >> 6, colb = off & 63;
        ushort4 u = {0, 0, 0, 0};
        if (colb < 48) {
            float4 v = *reinterpret_cast<const float4*>(w6 + row * 48 + colb);
            u.x = f2b(v.x); u.y = f2b(v.y); u.z = f2b(v.z); u.w = f2b(v.w);
        }
        *reinterpret_cast<ushort4*>(w6b + off) = u;
        return;
    }
    const float* src; unsigned short* dst; size_t off;
    if      (i4 < 1572864u) { src = x;  dst = xb;  off = i4; }
    else if (i4 < 3932160u) { src = w1; dst = w1b; off = i4 - 1572864u; }
    else if (i4 < 5111808u) { src = w2; dst = w2b; off = i4 - 3932160u; }
    else if (i4 < 7471104u) { src = w3; dst = w3b; off = i4 - 5111808u; }
    else if (i4 < 9830400u) { src = w4; dst = w4b; off = i4 - 7471104u; }
    else                    { src = w5; dst = w5b; off = i4 - 9830400u; }
    float4 v = *reinterpret_cast<const float4*>(src + off);
    ushort4 u;
    u.x = f2b(v.x); u.y = f2b(v.y); u.z = f2b(v.z); u.w = f2b(v.w);
    *reinterpret_cast<ushort4*>(dst + off) = u;
}

// ---------------------------------------------------------------------------
// Causal depthwise conv(4) + bias + SiLU, 4 channels per thread.
// ---------------------------------------------------------------------------
__global__ __launch_bounds__(256)
void conv_silu_k(const float* __restrict__ xin, const float* __restrict__ cw,
                 const float* __restrict__ cb, float* __restrict__ xc,
                 unsigned short* __restrict__ xcb)
{
    int q = blockIdx.x * 256 + threadIdx.x;
    int d4 = (q * 4) % DI;
    int bt = (q * 4) / DI;
    int t  = bt % SEQ;
    const float* base = xin + (size_t)bt * DI + d4;
    float4 s3 = *reinterpret_cast<const float4*>(base);
    float4 acc = *reinterpret_cast<const float4*>(cb + d4);
    float4 wv0 = *reinterpret_cast<const float4*>(cw + (d4 + 0) * 4);
    float4 wv1 = *reinterpret_cast<const float4*>(cw + (d4 + 1) * 4);
    float4 wv2 = *reinterpret_cast<const float4*>(cw + (d4 + 2) * 4);
    float4 wv3 = *reinterpret_cast<const float4*>(cw + (d4 + 3) * 4);
    acc.x += wv0.w * s3.x; acc.y += wv1.w * s3.y; acc.z += wv2.w * s3.z; acc.w += wv3.w * s3.w;
    if (t >= 1) {
        float4 s = *reinterpret_cast<const float4*>(base - DI);
        acc.x += wv0.z * s.x; acc.y += wv1.z * s.y; acc.z += wv2.z * s.z; acc.w += wv3.z * s.w;
    }
    if (t >= 2) {
        float4 s = *reinterpret_cast<const float4*>(base - 2 * DI);
        acc.x += wv0.y * s.x; acc.y += wv1.y * s.y; acc.z += wv2.y * s.z; acc.w += wv3.y * s.w;
    }
    if (t >= 3) {
        float4 s = *reinterpret_cast<const float4*>(base - 3 * DI);
        acc.x += wv0.x * s.x; acc.y += wv1.x * s.y; acc.z += wv2.x * s.z; acc.w += wv3.x * s.w;
    }
    float4 v;
    v.x = acc.x / (1.f + __expf(-acc.x));
    v.y = acc.y / (1.f + __expf(-acc.y));
    v.z = acc.z / (1.f + __expf(-acc.z));
    v.w = acc.w / (1.f + __expf(-acc.w));
    size_t o = (size_t)bt * DI + d4;
    *reinterpret_cast<float4*>(xc + o) = v;
    ushort4 u; u.x = f2b(v.x); u.y = f2b(v.y); u.z = f2b(v.z); u.w = f2b(v.w);
    *reinterpret_cast<ushort4*>(xcb + o) = u;
}

// ---------------------------------------------------------------------------
// scan2_a: per-chunk local scan (TCH=32), n-quad per thread.
// ---------------------------------------------------------------------------
__global__ __launch_bounds__(256)
void scan2_a(const float* __restrict__ delta, const float* __restrict__ xc,
             const float* __restrict__ xdbl,  const float* __restrict__ A_log,
             float* __restrict__ hfin, float* __restrict__ aprod)
{
    const int d0 = blockIdx.x * DBLK, ch = blockIdx.y, b = blockIdx.z;
    const int t0 = ch * TCH;
    __shared__ float del_s[TCH][DBLK + 4];
    __shared__ float xc_s[TCH][DBLK + 4];
    __shared__ float b_s[TCH][20];
    const int tid = threadIdx.x;
    {
        const int c4 = tid & 15, tr = tid >> 4;
        #pragma unroll
        for (int p = 0; p < 2; ++p) {
            int t = p * 16 + tr;
            size_t rowo = (size_t)(b * SEQ + t0 + t);
            *reinterpret_cast<float4*>(&del_s[t][c4 * 4]) =
                *reinterpret_cast<const float4*>(&delta[rowo * DI + d0 + c4 * 4]);
            *reinterpret_cast<float4*>(&xc_s[t][c4 * 4]) =
                *reinterpret_cast<const float4*>(&xc[rowo * DI + d0 + c4 * 4]);
        }
        const int cbq = tid & 3, tb = tid >> 2;
        if (tb < TCH) {
            size_t rowo = (size_t)(b * SEQ + t0 + tb);
            *reinterpret_cast<float4*>(&b_s[tb][cbq * 4]) =
                *reinterpret_cast<const float4*>(&xdbl[rowo * 80 + DTRANK + cbq * 4]);
        }
    }
    __syncthreads();
    const int lane = tid & 63, wave = tid >> 6;
    const int wd = wave * 16 + (lane >> 2);
    const int d = d0 + wd;
    const int nq = (lane & 3) * 4;
    float4 Av = *reinterpret_cast<const float4*>(&A_log[d * DSTATE + nq]);
    const float A0 = -__expf(Av.x), A1 = -__expf(Av.y), A2 = -__expf(Av.z), A3 = -__expf(Av.w);
    float h0_ = 0.f, h1_ = 0.f, h2_ = 0.f, h3_ = 0.f;
    float p0 = 1.f, p1 = 1.f, p2 = 1.f, p3 = 1.f;
    #pragma unroll 4
    for (int t = 0; t < TCH; ++t) {
        float dl = del_s[t][wd];
        float u  = dl * xc_s[t][wd];
        float4 bq = *reinterpret_cast<const float4*>(&b_s[t][nq]);
        float e0 = __expf(dl * A0), e1 = __expf(dl * A1);
        float e2 = __expf(dl * A2), e3 = __expf(dl * A3);
        h0_ = e0 * h0_ + u * bq.x; p0 *= e0;
        h1_ = e1 * h1_ + u * bq.y; p1 *= e1;
        h2_ = e2 * h2_ + u * bq.z; p2 *= e2;
        h3_ = e3 * h3_ + u * bq.w; p3 *= e3;
    }
    size_t o = ((size_t)((b * NCH + ch) * DI) + d) * DSTATE + nq;
    *reinterpret_cast<float4*>(&hfin[o])  = (float4){h0_, h1_, h2_, h3_};
    *reinterpret_cast<float4*>(&aprod[o]) = (float4){p0, p1, p2, p3};
}

// ---------------------------------------------------------------------------
// scan2_c: in-kernel chunk-prefix + full scan + reduce + gate (TCH=32).
// ---------------------------------------------------------------------------
__global__ __launch_bounds__(256)
void scan2_c(const float* __restrict__ delta, const float* __restrict__ xc,
             const float* __restrict__ xdbl,  const float* __restrict__ A_log,
             const float* __restrict__ Dp,    const unsigned short* __restrict__ zb,
             const float* __restrict__ hfin,  const float* __restrict__ aprod,
             unsigned short* __restrict__ yb)
{
    const int d0 = blockIdx.x * DBLK, ch = blockIdx.y, b = blockIdx.z;
    const int t0 = ch * TCH;
    __shared__ float del_s[TCH][DBLK + 4];
    __shared__ float xc_s[TCH][DBLK + 4];
    __shared__ float b_s[TCH][20];
    __shared__ float c_s[TCH][20];
    __shared__ unsigned short z_s[TCH][DBLK + 8];
    const int tid = threadIdx.x;
    {
        const int c4 = tid & 15, tr = tid >> 4;
        #pragma unroll
        for (int p = 0; p < 2; ++p) {
            int t = p * 16 + tr;
            size_t rowo = (size_t)(b * SEQ + t0 + t);
            *reinterpret_cast<float4*>(&del_s[t][c4 * 4]) =
                *reinterpret_cast<const float4*>(&delta[rowo * DI + d0 + c4 * 4]);
            *reinterpret_cast<float4*>(&xc_s[t][c4 * 4]) =
                *reinterpret_cast<const float4*>(&xc[rowo * DI + d0 + c4 * 4]);
        }
        const int cbq = tid & 3, tb = tid >> 2;
        if (tb < TCH) {
            size_t rowo = (size_t)(b * SEQ + t0 + tb);
            *reinterpret_cast<float4*>(&b_s[tb][cbq * 4]) =
                *reinterpret_cast<const float4*>(&xdbl[rowo * 80 + DTRANK + cbq * 4]);
        } else {
            size_t rowo = (size_t)(b * SEQ + t0 + tb - TCH);
            *reinterpret_cast<float4*>(&c_s[tb - TCH][cbq * 4]) =
                *reinterpret_cast<const float4*>(&xdbl[rowo * 80 + DTRANK + DSTATE + cbq * 4]);
        }
        const int cz = tid & 7, tz = tid >> 3;
        size_t rz = (size_t)(b * SEQ + t0 + tz);
        *reinterpret_cast<u32x4*>(&z_s[tz][cz * 8]) =
            *reinterpret_cast<const u32x4*>(&zb[rz * DI + d0 + cz * 8]);
    }
    const int lane = tid & 63, wave = tid >> 6;
    const int wd = wave * 16 + (lane >> 2);
    const int d = d0 + wd;
    const int nq = (lane & 3) * 4;

    // chunk-prefix recombine (global, overlaps with staging)
    float4 h = {0.f, 0.f, 0.f, 0.f};
    for (int cc = 0; cc < ch; ++cc) {
        size_t o = ((size_t)((b * NCH + cc) * DI) + d) * DSTATE + nq;
        float4 a = *reinterpret_cast<const float4*>(&aprod[o]);
        float4 f = *reinterpret_cast<const float4*>(&hfin[o]);
        h.x = a.x * h.x + f.x; h.y = a.y * h.y + f.y;
        h.z = a.z * h.z + f.z; h.w = a.w * h.w + f.w;
    }

    float4 Av = *reinterpret_cast<const float4*>(&A_log[d * DSTATE + nq]);
    const float A0 = -__expf(Av.x), A1 = -__expf(Av.y), A2 = -__expf(Av.z), A3 = -__expf(Av.w);
    const float Dd = Dp[d];
    __syncthreads();
    unsigned short* yrow = yb + (size_t)(b * SEQ + t0) * DI + d;
    #pragma unroll 4
    for (int t = 0; t < TCH; ++t) {
        float dl = del_s[t][wd];
        float xv = xc_s[t][wd];
        float u  = dl * xv;
        float4 bq = *reinterpret_cast<const float4*>(&b_s[t][nq]);
        float4 cq = *reinterpret_cast<const float4*>(&c_s[t][nq]);
        float e0 = __expf(dl * A0), e1 = __expf(dl * A1);
        float e2 = __expf(dl * A2), e3 = __expf(dl * A3);
        h.x = e0 * h.x + u * bq.x;
        h.y = e1 * h.y + u * bq.y;
        h.z = e2 * h.z + u * bq.z;
        h.w = e3 * h.w + u * bq.w;
        float py = h.x * cq.x + h.y * cq.y + h.z * cq.z + h.w * cq.w;
        py += __shfl_xor(py, 1);
        py += __shfl_xor(py, 2);
        if ((lane & 3) == 0) {
            float yv = py + xv * Dd;
            float zv = b2f(z_s[t][wd]);
            yv *= zv / (1.f + __expf(-zv));
            yrow[(size_t)t * DI] = f2b(yv);
        }
    }
}

// ---------------------------------------------------------------------------
extern "C" void kernel_launch(void* const* d_in, const int* in_sizes, int n_in,
                              void* d_out, int out_size, void* d_ws, size_t ws_size,
                              hipStream_t stream)
{
    const float* x         = (const float*)d_in[0];
    const float* in_proj_w = (const float*)d_in[1];
    const float* conv_w    = (const float*)d_in[2];
    const float* conv_b    = (const float*)d_in[3];
    const float* x_proj_w  = (const float*)d_in[4];
    const float* dt_proj_w = (const float*)d_in[5];
    const float* dt_proj_b = (const float*)d_in[6];
    const float* A_log     = (const float*)d_in[7];
    const float* D_param   = (const float*)d_in[8];
    const float* out_proj_w= (const float*)d_in[9];
    const float* ln1_w     = (const float*)d_in[10];
    const float* ln1_b     = (const float*)d_in[11];
    const float* ln2_w     = (const float*)d_in[12];
    const float* ln2_b     = (const float*)d_in[13];
    const float* ffn_w1    = (const float*)d_in[14];
    const float* ffn_b1    = (const float*)d_in[15];
    const float* ffn_w2    = (const float*)d_in[16];
    const float* ffn_b2    = (const float*)d_in[17];
    float* out = (float*)d_out;

    char* Wp = (char*)d_ws;
    // static regions (lifetimes in step numbers)
    float*          xin   = (float*)         (Wp + 0);          // [2-3]
    unsigned short* zbuf  = (unsigned short*)(Wp + 12582912);   // [2-7]
    float*          xc    = (float*)         (Wp + 18874368);   // [3-7]
    float*          xdbl  = (float*)         (Wp + 31457280);   // [4b-7]
    float*          delta = (float*)         (Wp + 32112640);   // [5-7]
    unsigned short* ybb   = (unsigned short*)(Wp + 44695552);   // [7-8]
    unsigned short* xb    = (unsigned short*)(Wp + 58851328);   // [1-2]
    unsigned short* wib   = (unsigned short*)(Wp + 61997056);   // [1-2]
    unsigned short* wob   = (unsigned short*)(Wp + 66715648);   // [1-8]
    unsigned short* wf1b  = (unsigned short*)(Wp + 69074944);   // [1-10]
    unsigned short* wf2b  = (unsigned short*)(Wp + 73793536);   // [1-11]
    // aliases into dead regions:
    unsigned short* fbf   = (unsigned short*)(Wp + 0);          // [10-11]
    float*          x1    = (float*)         (Wp + 32112640);   // [9-12] (delta dead)
    unsigned short* x1b   = (unsigned short*)(Wp + 58851328);   // [9-10] (xb dead)
    float*          part  = (float*)         (Wp + 0);          // [4a-4b]
    unsigned short* xdblb = (unsigned short*)(Wp + 5242880);    // [4b-5]
    unsigned short* xcb   = (unsigned short*)(Wp + 58851328);   // [3-4a] (xb/wib dead)
    unsigned short* xpwb  = (unsigned short*)(Wp + 50987008);   // [1-4a]
    unsigned short* wdtb  = (unsigned short*)(Wp + 51232768);   // [1-5]
    // scan state (NCH=32): 6.29 MB each
    float*          hfin  = (float*)         (Wp + 0);          // [6a-7] (xin/part dead)
    float*          aprod = (float*)         (Wp + 6291456);    // [6a-7]
    // split-K partials (4 x 6.29 MB):
    float*          part_op = (float*)       (Wp + 0);          // [8a-8b] (hfin/aprod dead)
    float*          part_f2 = (float*)       (Wp + 38404096);   // [11a-11b] (x1 ends 38404096)

    dim3 blk(256);

    // 1. bf16 conversions (all weights + x, incl. padded dt_proj_w)
    cvt7_k<<<9816, blk, 0, stream>>>(x, in_proj_w, out_proj_w, ffn_w1, ffn_w2, x_proj_w,
                                     dt_proj_w, xb, wib, wob, wf1b, wf2b, xpwb, wdtb);

    // 2. in_proj: xin f32 + z bf16   [2048,3072] K=768
    gemm_b<5, 1><<<dim3(24, 16, 1), blk, 0, stream>>>(xb, wib, xin, zbuf, nullptr,
                                                      NROWS, 2 * DI, EMBED, nullptr);

    // 3. conv + silu -> xc f32 + xcb bf16
    conv_silu_k<<<(BATCH * SEQ * DI) / 1024, blk, 0, stream>>>(xin, conv_w, conv_b, xc, xcb);

    // 4. x_proj split-K MFMA + reduce
    xproj_mfma<<<dim3(16, 8), blk, 0, stream>>>(xcb, xpwb, part);
    xproj_reduce<<<640, blk, 0, stream>>>(part, xdbl, xdblb);

    // 5. dt_proj + softplus -> delta f32   [2048,1536] K=64
    gemm_b<1, 1><<<dim3(12, 16, 1), blk, 0, stream>>>(xdblb, wdtb, delta, nullptr, nullptr,
                                                      NROWS, DI, 64, dt_proj_b);

    // 6. chunked scan (TCH=32): local scans, then prefix+finish
    scan2_a<<<dim3(DI / DBLK, NCH, BATCH), blk, 0, stream>>>(delta, xc, xdbl, A_log, hfin, aprod);
    scan2_c<<<dim3(DI / DBLK, NCH, BATCH), blk, 0, stream>>>(delta, xc, xdbl, A_log, D_param,
                                                             zbuf, hfin, aprod, ybb);

    // 8. out_proj split-K(4) -> partials; fused reduce+resid+LN1 -> x1 + x1b
    gemm_b<0, 4><<<dim3(6, 16, 4), blk, 0, stream>>>(ybb, wob, nullptr, nullptr, part_op,
                                                     NROWS, EMBED, DI, nullptr);
    reduce_ln<4, 0><<<NROWS, blk, 0, stream>>>(part_op, x, nullptr, ln1_w, ln1_b, x1, x1b);

    // 10. ffn1 + gelu -> fbf bf16   [2048,3072] K=768
    gemm_b<3, 1><<<dim3(24, 16, 1), blk, 0, stream>>>(x1b, wf1b, nullptr, fbf, nullptr,
                                                      NROWS, FF, EMBED, ffn_b1);

    // 11. ffn2 split-K(4) -> partials; fused reduce+bias+resid+LN2 -> out
    gemm_b<0, 4><<<dim3(6, 16, 4), blk, 0, stream>>>(fbf, wf2b, nullptr, nullptr, part_f2,
                                                     NROWS, EMBED, FF, nullptr);
    reduce_ln<4, 1><<<NROWS, blk, 0, stream>>>(part_f2, x1, ffn_b2, ln2_w, ln2_b, out, nullptr);
}

// Round 9
// 208.461 us; speedup vs baseline: 1.1027x; 1.1027x over previous
//
#include <hip/hip_runtime.h>
#include <math.h>

#define EMBED 768
#define DI 1536
#define DSTATE 16
#define DCONV 4
#define DTRANK 48
#define FF 3072
#define BATCH 2
#define SEQ 1024
#define NROWS (BATCH*SEQ)
#define TCH 32
#define NCH (SEQ/TCH)
#define DBLK 64

typedef __bf16 bf16x8 __attribute__((ext_vector_type(8)));
typedef float f32x4 __attribute__((ext_vector_type(4)));
typedef unsigned int u32x4 __attribute__((ext_vector_type(4)));

static __device__ __forceinline__ unsigned short f2b(float f) {
    union { float f; unsigned u; } v; v.f = f;
    unsigned r = v.u + 0x7FFFu + ((v.u >> 16) & 1u);
    return (unsigned short)(r >> 16);
}
static __device__ __forceinline__ float b2f(unsigned short s) {
    union { unsigned u; float f; } v; v.u = ((unsigned)s) << 16;
    return v.f;
}

#define GLOAD_LDS16(g, l) __builtin_amdgcn_global_load_lds( \
    (const __attribute__((address_space(1))) void*)(g), \
    (__attribute__((address_space(3))) void*)(l), 16, 0, 0)

// ---------------------------------------------------------------------------
// gemm_sk: C[M,N] = A[M,K](bf16) @ W[N,K](bf16)^T, 128x64 tile, BK=32.
// (round-7 proven: 768-block grids, 12 KB LDS, ~3 blocks/CU)
// ---------------------------------------------------------------------------
template<int EPI, int KSPLIT>
__global__ __launch_bounds__(256)
void gemm_sk(const unsigned short* __restrict__ A,
             const unsigned short* __restrict__ W,
             float* __restrict__ C, unsigned short* __restrict__ Cb,
             float* __restrict__ part,
             int M, int N, int K,
             const float* __restrict__ bias)
{
    __shared__ alignas(16) unsigned short As[128 * 32];
    __shared__ alignas(16) unsigned short Ws[64 * 32];
    const int tid  = threadIdx.x;
    const int lane = tid & 63, wave = tid >> 6;
    const int bm = blockIdx.y * 128, bn = blockIdx.x * 64;
    const int kc = K / KSPLIT;
    const int kz = blockIdx.z * kc;
    const int ln = lane & 15, lg = lane >> 4;

    f32x4 acc[2][4];
    #pragma unroll
    for (int i = 0; i < 2; ++i)
        #pragma unroll
        for (int j = 0; j < 4; ++j)
            acc[i][j] = (f32x4){0.f, 0.f, 0.f, 0.f};

    const int ra = tid >> 2, ca = tid & 3;
    const int cs = (ca * 8) ^ ((ra & 3) << 3);
    const unsigned short* gA0 = A + (size_t)(bm + ra) * K + kz + cs;
    const unsigned short* gA1 = A + (size_t)(bm + ra + 64) * K + kz + cs;
    const unsigned short* gW  = W + (size_t)(bn + ra) * K + kz + cs;
    unsigned short* ldsA0 = As + wave * 512;
    unsigned short* ldsA1 = As + 2048 + wave * 512;
    unsigned short* ldsW  = Ws + wave * 512;

    for (int k0 = 0; k0 < kc; k0 += 32) {
        GLOAD_LDS16(gA0 + k0, ldsA0);
        GLOAD_LDS16(gA1 + k0, ldsA1);
        GLOAD_LDS16(gW  + k0, ldsW);
        __syncthreads();
        bf16x8 af[2], wf[4];
        #pragma unroll
        for (int i = 0; i < 2; ++i) {
            int row = wave * 32 + i * 16 + ln;
            af[i] = *reinterpret_cast<const bf16x8*>(
                &As[row * 32 + ((lg * 8) ^ ((row & 3) << 3))]);
        }
        #pragma unroll
        for (int j = 0; j < 4; ++j) {
            int row = j * 16 + ln;
            wf[j] = *reinterpret_cast<const bf16x8*>(
                &Ws[row * 32 + ((lg * 8) ^ ((row & 3) << 3))]);
        }
        #pragma unroll
        for (int i = 0; i < 2; ++i)
            #pragma unroll
            for (int j = 0; j < 4; ++j)
                acc[i][j] = __builtin_amdgcn_mfma_f32_16x16x32_bf16(af[i], wf[j], acc[i][j], 0, 0, 0);
        __syncthreads();
    }

    if constexpr (KSPLIT > 1) {
        float* pb = part + (size_t)blockIdx.z * M * N;
        #pragma unroll
        for (int i = 0; i < 2; ++i)
            #pragma unroll
            for (int j = 0; j < 4; ++j) {
                int col = bn + j * 16 + ln;
                #pragma unroll
                for (int rr = 0; rr < 4; ++rr) {
                    int row = bm + wave * 32 + i * 16 + lg * 4 + rr;
                    pb[(size_t)row * N + col] = acc[i][j][rr];
                }
            }
    } else {
        #pragma unroll
        for (int i = 0; i < 2; ++i)
            #pragma unroll
            for (int j = 0; j < 4; ++j) {
                int col = bn + j * 16 + ln;
                #pragma unroll
                for (int rr = 0; rr < 4; ++rr) {
                    int row = bm + wave * 32 + i * 16 + lg * 4 + rr;
                    float v = acc[i][j][rr];
                    size_t o = (size_t)row * N + col;
                    if (EPI == 1) {
                        v += bias[col];
                        C[o] = (v > 20.f) ? v : log1pf(expf(v));
                    } else if (EPI == 3) {
                        v += bias[col];
                        float t = 0.7978845608028654f * (v + 0.044715f * v * v * v);
                        Cb[o] = f2b(0.5f * v * (1.f + tanhf(t)));
                    } else if (EPI == 5) {
                        if (col < DI) C[(size_t)row * DI + col] = v;
                        else          Cb[(size_t)row * DI + col - DI] = f2b(v);
                    } else {
                        C[o] = v;
                    }
                }
            }
    }
}

// ---------------------------------------------------------------------------
// reduce_ln: sum KS split-K partials (+bias) (+resid), then LayerNorm(768).
// ---------------------------------------------------------------------------
template<int KS, int BIAS>
__global__ __launch_bounds__(256)
void reduce_ln(const float* __restrict__ part, const float* __restrict__ resid,
               const float* __restrict__ bias,
               const float* __restrict__ w, const float* __restrict__ bb,
               float* __restrict__ out, unsigned short* __restrict__ outb)
{
    const int row = blockIdx.x;
    const size_t ro = (size_t)row * EMBED;
    const int i0 = threadIdx.x, i1 = i0 + 256, i2 = i0 + 512;
    float v0 = 0.f, v1 = 0.f, v2 = 0.f;
    #pragma unroll
    for (int z = 0; z < KS; ++z) {
        const float* p = part + (size_t)z * NROWS * EMBED + ro;
        v0 += p[i0]; v1 += p[i1]; v2 += p[i2];
    }
    if (BIAS) { v0 += bias[i0]; v1 += bias[i1]; v2 += bias[i2]; }
    v0 += resid[ro + i0]; v1 += resid[ro + i1]; v2 += resid[ro + i2];

    float s  = v0 + v1 + v2;
    float s2 = v0 * v0 + v1 * v1 + v2 * v2;
    #pragma unroll
    for (int m = 1; m < 64; m <<= 1) {
        s  += __shfl_xor(s,  m);
        s2 += __shfl_xor(s2, m);
    }
    __shared__ float sh1[4], sh2[4];
    int wv = threadIdx.x >> 6;
    if ((threadIdx.x & 63) == 0) { sh1[wv] = s; sh2[wv] = s2; }
    __syncthreads();
    float S1 = sh1[0] + sh1[1] + sh1[2] + sh1[3];
    float S2 = sh2[0] + sh2[1] + sh2[2] + sh2[3];
    float mu  = S1 * (1.f / EMBED);
    float var = S2 * (1.f / EMBED) - mu * mu;
    float rs  = rsqrtf(var + 1e-5f);
    float o0 = (v0 - mu) * rs * w[i0] + bb[i0];
    float o1 = (v1 - mu) * rs * w[i1] + bb[i1];
    float o2 = (v2 - mu) * rs * w[i2] + bb[i2];
    out[ro + i0] = o0; out[ro + i1] = o1; out[ro + i2] = o2;
    if (outb) {
        outb[ro + i0] = f2b(o0); outb[ro + i1] = f2b(o1); outb[ro + i2] = f2b(o2);
    }
}

// ---------------------------------------------------------------------------
// x_proj split-K MFMA + reduce
// ---------------------------------------------------------------------------
__global__ __launch_bounds__(256)
void xproj_mfma(const unsigned short* __restrict__ A,
                const unsigned short* __restrict__ W,
                float* __restrict__ part)
{
    const int mt = blockIdx.x, s = blockIdx.y;
    const int lane = threadIdx.x & 63, wave = threadIdx.x >> 6;
    const int ln = lane & 15, lg = lane >> 4;
    const int row0 = mt * 128 + wave * 32;
    const int kb = s * 192;
    f32x4 acc[2][5];
    #pragma unroll
    for (int i = 0; i < 2; ++i)
        #pragma unroll
        for (int j = 0; j < 5; ++j)
            acc[i][j] = (f32x4){0.f, 0.f, 0.f, 0.f};

    for (int kk = 0; kk < 192; kk += 32) {
        const int k = kb + kk + lg * 8;
        bf16x8 af[2], wf[5];
        af[0] = *reinterpret_cast<const bf16x8*>(A + (size_t)(row0 + ln) * DI + k);
        af[1] = *reinterpret_cast<const bf16x8*>(A + (size_t)(row0 + 16 + ln) * DI + k);
        #pragma unroll
        for (int j = 0; j < 5; ++j)
            wf[j] = *reinterpret_cast<const bf16x8*>(W + (size_t)(j * 16 + ln) * DI + k);
        #pragma unroll
        for (int i = 0; i < 2; ++i)
            #pragma unroll
            for (int j = 0; j < 5; ++j)
                acc[i][j] = __builtin_amdgcn_mfma_f32_16x16x32_bf16(af[i], wf[j], acc[i][j], 0, 0, 0);
    }
    float* pb = part + (size_t)s * NROWS * 80;
    #pragma unroll
    for (int i = 0; i < 2; ++i)
        #pragma unroll
        for (int j = 0; j < 5; ++j)
            #pragma unroll
            for (int rr = 0; rr < 4; ++rr) {
                int row = row0 + i * 16 + lg * 4 + rr;
                int col = j * 16 + ln;
                pb[(size_t)row * 80 + col] = acc[i][j][rr];
            }
}

__global__ __launch_bounds__(256)
void xproj_reduce(const float* __restrict__ part, float* __restrict__ xdbl,
                  unsigned short* __restrict__ xdblb)
{
    int idx = blockIdx.x * 256 + threadIdx.x;      // 163840
    float sum = 0.f;
    #pragma unroll
    for (int s = 0; s < 8; ++s) sum += part[(size_t)s * NROWS * 80 + idx];
    xdbl[idx] = sum;
    int col = idx % 80, row = idx / 80;
    if (col < 48)      xdblb[row * 64 + col] = f2b(sum);
    else if (col < 64) xdblb[row * 64 + col] = 0;
}

// ---------------------------------------------------------------------------
// f32 -> bf16 conversion: x + 4 big weights + x_proj_w + padded dt_proj_w.
// ---------------------------------------------------------------------------
__global__ __launch_bounds__(256)
void cvt7_k(const float* __restrict__ x,  const float* __restrict__ w1,
            const float* __restrict__ w2, const float* __restrict__ w3,
            const float* __restrict__ w4, const float* __restrict__ w5,
            const float* __restrict__ w6,
            unsigned short* __restrict__ xb,  unsigned short* __restrict__ w1b,
            unsigned short* __restrict__ w2b, unsigned short* __restrict__ w3b,
            unsigned short* __restrict__ w4b, unsigned short* __restrict__ w5b,
            unsigned short* __restrict__ w6b)
{
    size_t i4 = ((size_t)blockIdx.x * 256 + threadIdx.x) * 4;
    if (i4 >= 9953280u) {
        int off = (int)(i4 - 9953280u);
        if (off >= 98304) return;
        int row = off >> 6, colb = off & 63;
        ushort4 u = {0, 0, 0, 0};
        if (colb < 48) {
            float4 v = *reinterpret_cast<const float4*>(w6 + row * 48 + colb);
            u.x = f2b(v.x); u.y = f2b(v.y); u.z = f2b(v.z); u.w = f2b(v.w);
        }
        *reinterpret_cast<ushort4*>(w6b + off) = u;
        return;
    }
    const float* src; unsigned short* dst; size_t off;
    if      (i4 < 1572864u) { src = x;  dst = xb;  off = i4; }
    else if (i4 < 3932160u) { src = w1; dst = w1b; off = i4 - 1572864u; }
    else if (i4 < 5111808u) { src = w2; dst = w2b; off = i4 - 3932160u; }
    else if (i4 < 7471104u) { src = w3; dst = w3b; off = i4 - 5111808u; }
    else if (i4 < 9830400u) { src = w4; dst = w4b; off = i4 - 7471104u; }
    else                    { src = w5; dst = w5b; off = i4 - 9830400u; }
    float4 v = *reinterpret_cast<const float4*>(src + off);
    ushort4 u;
    u.x = f2b(v.x); u.y = f2b(v.y); u.z = f2b(v.z); u.w = f2b(v.w);
    *reinterpret_cast<ushort4*>(dst + off) = u;
}

// ---------------------------------------------------------------------------
// Causal depthwise conv(4) + bias + SiLU, 4 channels per thread.
// ---------------------------------------------------------------------------
__global__ __launch_bounds__(256)
void conv_silu_k(const float* __restrict__ xin, const float* __restrict__ cw,
                 const float* __restrict__ cb, float* __restrict__ xc,
                 unsigned short* __restrict__ xcb)
{
    int q = blockIdx.x * 256 + threadIdx.x;
    int d4 = (q * 4) % DI;
    int bt = (q * 4) / DI;
    int t  = bt % SEQ;
    const float* base = xin + (size_t)bt * DI + d4;
    float4 s3 = *reinterpret_cast<const float4*>(base);
    float4 acc = *reinterpret_cast<const float4*>(cb + d4);
    float4 wv0 = *reinterpret_cast<const float4*>(cw + (d4 + 0) * 4);
    float4 wv1 = *reinterpret_cast<const float4*>(cw + (d4 + 1) * 4);
    float4 wv2 = *reinterpret_cast<const float4*>(cw + (d4 + 2) * 4);
    float4 wv3 = *reinterpret_cast<const float4*>(cw + (d4 + 3) * 4);
    acc.x += wv0.w * s3.x; acc.y += wv1.w * s3.y; acc.z += wv2.w * s3.z; acc.w += wv3.w * s3.w;
    if (t >= 1) {
        float4 s = *reinterpret_cast<const float4*>(base - DI);
        acc.x += wv0.z * s.x; acc.y += wv1.z * s.y; acc.z += wv2.z * s.z; acc.w += wv3.z * s.w;
    }
    if (t >= 2) {
        float4 s = *reinterpret_cast<const float4*>(base - 2 * DI);
        acc.x += wv0.y * s.x; acc.y += wv1.y * s.y; acc.z += wv2.y * s.z; acc.w += wv3.y * s.w;
    }
    if (t >= 3) {
        float4 s = *reinterpret_cast<const float4*>(base - 3 * DI);
        acc.x += wv0.x * s.x; acc.y += wv1.x * s.y; acc.z += wv2.x * s.z; acc.w += wv3.x * s.w;
    }
    float4 v;
    v.x = acc.x / (1.f + __expf(-acc.x));
    v.y = acc.y / (1.f + __expf(-acc.y));
    v.z = acc.z / (1.f + __expf(-acc.z));
    v.w = acc.w / (1.f + __expf(-acc.w));
    size_t o = (size_t)bt * DI + d4;
    *reinterpret_cast<float4*>(xc + o) = v;
    ushort4 u; u.x = f2b(v.x); u.y = f2b(v.y); u.z = f2b(v.z); u.w = f2b(v.w);
    *reinterpret_cast<ushort4*>(xcb + o) = u;
}

// ---------------------------------------------------------------------------
// scan2_a: per-chunk local scan (TCH=32), n-quad per thread.
// ---------------------------------------------------------------------------
__global__ __launch_bounds__(256)
void scan2_a(const float* __restrict__ delta, const float* __restrict__ xc,
             const float* __restrict__ xdbl,  const float* __restrict__ A_log,
             float* __restrict__ hfin, float* __restrict__ aprod)
{
    const int d0 = blockIdx.x * DBLK, ch = blockIdx.y, b = blockIdx.z;
    const int t0 = ch * TCH;
    __shared__ float del_s[TCH][DBLK + 4];
    __shared__ float xc_s[TCH][DBLK + 4];
    __shared__ float b_s[TCH][20];
    const int tid = threadIdx.x;
    {
        const int c4 = tid & 15, tr = tid >> 4;
        #pragma unroll
        for (int p = 0; p < 2; ++p) {
            int t = p * 16 + tr;
            size_t rowo = (size_t)(b * SEQ + t0 + t);
            *reinterpret_cast<float4*>(&del_s[t][c4 * 4]) =
                *reinterpret_cast<const float4*>(&delta[rowo * DI + d0 + c4 * 4]);
            *reinterpret_cast<float4*>(&xc_s[t][c4 * 4]) =
                *reinterpret_cast<const float4*>(&xc[rowo * DI + d0 + c4 * 4]);
        }
        const int cbq = tid & 3, tb = tid >> 2;
        if (tb < TCH) {
            size_t rowo = (size_t)(b * SEQ + t0 + tb);
            *reinterpret_cast<float4*>(&b_s[tb][cbq * 4]) =
                *reinterpret_cast<const float4*>(&xdbl[rowo * 80 + DTRANK + cbq * 4]);
        }
    }
    __syncthreads();
    const int lane = tid & 63, wave = tid >> 6;
    const int wd = wave * 16 + (lane >> 2);
    const int d = d0 + wd;
    const int nq = (lane & 3) * 4;
    float4 Av = *reinterpret_cast<const float4*>(&A_log[d * DSTATE + nq]);
    const float A0 = -__expf(Av.x), A1 = -__expf(Av.y), A2 = -__expf(Av.z), A3 = -__expf(Av.w);
    float h0_ = 0.f, h1_ = 0.f, h2_ = 0.f, h3_ = 0.f;
    float p0 = 1.f, p1 = 1.f, p2 = 1.f, p3 = 1.f;
    #pragma unroll 4
    for (int t = 0; t < TCH; ++t) {
        float dl = del_s[t][wd];
        float u  = dl * xc_s[t][wd];
        float4 bq = *reinterpret_cast<const float4*>(&b_s[t][nq]);
        float e0 = __expf(dl * A0), e1 = __expf(dl * A1);
        float e2 = __expf(dl * A2), e3 = __expf(dl * A3);
        h0_ = e0 * h0_ + u * bq.x; p0 *= e0;
        h1_ = e1 * h1_ + u * bq.y; p1 *= e1;
        h2_ = e2 * h2_ + u * bq.z; p2 *= e2;
        h3_ = e3 * h3_ + u * bq.w; p3 *= e3;
    }
    size_t o = ((size_t)((b * NCH + ch) * DI) + d) * DSTATE + nq;
    *reinterpret_cast<float4*>(&hfin[o])  = (float4){h0_, h1_, h2_, h3_};
    *reinterpret_cast<float4*>(&aprod[o]) = (float4){p0, p1, p2, p3};
}

// ---------------------------------------------------------------------------
// scan2_b: serial combine over chunks, float4 per thread (one n-quad).
// ---------------------------------------------------------------------------
__global__ __launch_bounds__(256)
void scan2_b(const float* __restrict__ hfin, const float* __restrict__ aprod,
             float* __restrict__ h0)
{
    int idx = blockIdx.x * 256 + threadIdx.x;      // B*DI*4 = 12288
    int nq = (idx & 3) * 4;
    int d  = (idx >> 2) % DI;
    int b  = (idx >> 2) / DI;
    float4 h = {0.f, 0.f, 0.f, 0.f};
    #pragma unroll
    for (int ch = 0; ch < NCH; ++ch) {
        size_t o = ((size_t)((b * NCH + ch) * DI) + d) * DSTATE + nq;
        *reinterpret_cast<float4*>(&h0[o]) = h;
        float4 a = *reinterpret_cast<const float4*>(&aprod[o]);
        float4 f = *reinterpret_cast<const float4*>(&hfin[o]);
        h.x = a.x * h.x + f.x; h.y = a.y * h.y + f.y;
        h.z = a.z * h.z + f.z; h.w = a.w * h.w + f.w;
    }
}

// ---------------------------------------------------------------------------
// scan2_c: full scan from h0 with reduce + gate (TCH=32), n-quad per thread.
// ---------------------------------------------------------------------------
__global__ __launch_bounds__(256)
void scan2_c(const float* __restrict__ delta, const float* __restrict__ xc,
             const float* __restrict__ xdbl,  const float* __restrict__ A_log,
             const float* __restrict__ Dp,    const unsigned short* __restrict__ zb,
             const float* __restrict__ h0,
             unsigned short* __restrict__ yb)
{
    const int d0 = blockIdx.x * DBLK, ch = blockIdx.y, b = blockIdx.z;
    const int t0 = ch * TCH;
    __shared__ float del_s[TCH][DBLK + 4];
    __shared__ float xc_s[TCH][DBLK + 4];
    __shared__ float b_s[TCH][20];
    __shared__ float c_s[TCH][20];
    __shared__ unsigned short z_s[TCH][DBLK + 8];
    const int tid = threadIdx.x;
    {
        const int c4 = tid & 15, tr = tid >> 4;
        #pragma unroll
        for (int p = 0; p < 2; ++p) {
            int t = p * 16 + tr;
            size_t rowo = (size_t)(b * SEQ + t0 + t);
            *reinterpret_cast<float4*>(&del_s[t][c4 * 4]) =
                *reinterpret_cast<const float4*>(&delta[rowo * DI + d0 + c4 * 4]);
            *reinterpret_cast<float4*>(&xc_s[t][c4 * 4]) =
                *reinterpret_cast<const float4*>(&xc[rowo * DI + d0 + c4 * 4]);
        }
        const int cbq = tid & 3, tb = tid >> 2;
        if (tb < TCH) {
            size_t rowo = (size_t)(b * SEQ + t0 + tb);
            *reinterpret_cast<float4*>(&b_s[tb][cbq * 4]) =
                *reinterpret_cast<const float4*>(&xdbl[rowo * 80 + DTRANK + cbq * 4]);
        } else {
            size_t rowo = (size_t)(b * SEQ + t0 + tb - TCH);
            *reinterpret_cast<float4*>(&c_s[tb - TCH][cbq * 4]) =
                *reinterpret_cast<const float4*>(&xdbl[rowo * 80 + DTRANK + DSTATE + cbq * 4]);
        }
        const int cz = tid & 7, tz = tid >> 3;
        size_t rz = (size_t)(b * SEQ + t0 + tz);
        *reinterpret_cast<u32x4*>(&z_s[tz][cz * 8]) =
            *reinterpret_cast<const u32x4*>(&zb[rz * DI + d0 + cz * 8]);
    }
    __syncthreads();
    const int lane = tid & 63, wave = tid >> 6;
    const int wd = wave * 16 + (lane >> 2);
    const int d = d0 + wd;
    const int nq = (lane & 3) * 4;
    float4 Av = *reinterpret_cast<const float4*>(&A_log[d * DSTATE + nq]);
    const float A0 = -__expf(Av.x), A1 = -__expf(Av.y), A2 = -__expf(Av.z), A3 = -__expf(Av.w);
    const float Dd = Dp[d];
    float4 h = *reinterpret_cast<const float4*>(
        &h0[((size_t)((b * NCH + ch) * DI) + d) * DSTATE + nq]);
    unsigned short* yrow = yb + (size_t)(b * SEQ + t0) * DI + d;
    #pragma unroll 4
    for (int t = 0; t < TCH; ++t) {
        float dl = del_s[t][wd];
        float xv = xc_s[t][wd];
        float u  = dl * xv;
        float4 bq = *reinterpret_cast<const float4*>(&b_s[t][nq]);
        float4 cq = *reinterpret_cast<const float4*>(&c_s[t][nq]);
        float e0 = __expf(dl * A0), e1 = __expf(dl * A1);
        float e2 = __expf(dl * A2), e3 = __expf(dl * A3);
        h.x = e0 * h.x + u * bq.x;
        h.y = e1 * h.y + u * bq.y;
        h.z = e2 * h.z + u * bq.z;
        h.w = e3 * h.w + u * bq.w;
        float py = h.x * cq.x + h.y * cq.y + h.z * cq.z + h.w * cq.w;
        py += __shfl_xor(py, 1);
        py += __shfl_xor(py, 2);
        if ((lane & 3) == 0) {
            float yv = py + xv * Dd;
            float zv = b2f(z_s[t][wd]);
            yv *= zv / (1.f + __expf(-zv));
            yrow[(size_t)t * DI] = f2b(yv);
        }
    }
}

// ---------------------------------------------------------------------------
extern "C" void kernel_launch(void* const* d_in, const int* in_sizes, int n_in,
                              void* d_out, int out_size, void* d_ws, size_t ws_size,
                              hipStream_t stream)
{
    const float* x         = (const float*)d_in[0];
    const float* in_proj_w = (const float*)d_in[1];
    const float* conv_w    = (const float*)d_in[2];
    const float* conv_b    = (const float*)d_in[3];
    const float* x_proj_w  = (const float*)d_in[4];
    const float* dt_proj_w = (const float*)d_in[5];
    const float* dt_proj_b = (const float*)d_in[6];
    const float* A_log     = (const float*)d_in[7];
    const float* D_param   = (const float*)d_in[8];
    const float* out_proj_w= (const float*)d_in[9];
    const float* ln1_w     = (const float*)d_in[10];
    const float* ln1_b     = (const float*)d_in[11];
    const float* ln2_w     = (const float*)d_in[12];
    const float* ln2_b     = (const float*)d_in[13];
    const float* ffn_w1    = (const float*)d_in[14];
    const float* ffn_b1    = (const float*)d_in[15];
    const float* ffn_w2    = (const float*)d_in[16];
    const float* ffn_b2    = (const float*)d_in[17];
    float* out = (float*)d_out;

    char* Wp = (char*)d_ws;
    // static regions (lifetimes in step numbers)
    float*          xin   = (float*)         (Wp + 0);          // [2-3]
    unsigned short* zbuf  = (unsigned short*)(Wp + 12582912);   // [2-7]
    float*          xc    = (float*)         (Wp + 18874368);   // [3-7]
    float*          xdbl  = (float*)         (Wp + 31457280);   // [4b-7]
    float*          delta = (float*)         (Wp + 32112640);   // [5-7]
    unsigned short* ybb   = (unsigned short*)(Wp + 44695552);   // [7-8]
    unsigned short* xb    = (unsigned short*)(Wp + 58851328);   // [1-2]
    unsigned short* wib   = (unsigned short*)(Wp + 61997056);   // [1-2]
    unsigned short* wob   = (unsigned short*)(Wp + 66715648);   // [1-8]
    unsigned short* wf1b  = (unsigned short*)(Wp + 69074944);   // [1-10]
    unsigned short* wf2b  = (unsigned short*)(Wp + 73793536);   // [1-11]
    // aliases into dead regions:
    unsigned short* fbf   = (unsigned short*)(Wp + 0);          // [10-11]
    float*          x1    = (float*)         (Wp + 32112640);   // [9-12] (delta dead)
    unsigned short* x1b   = (unsigned short*)(Wp + 58851328);   // [9-10] (xb dead)
    float*          part  = (float*)         (Wp + 0);          // [4a-4b]
    unsigned short* xdblb = (unsigned short*)(Wp + 5242880);    // [4b-5]
    unsigned short* xcb   = (unsigned short*)(Wp + 58851328);   // [3-4a] (xb/wib dead)
    unsigned short* xpwb  = (unsigned short*)(Wp + 50987008);   // [1-4a]
    unsigned short* wdtb  = (unsigned short*)(Wp + 51232768);   // [1-5]
    // scan state (NCH=32): 6.29 MB each
    float*          hfin  = (float*)         (Wp + 0);          // [6a-6c] (xin/part dead)
    float*          aprod = (float*)         (Wp + 6291456);    // [6a-6c]
    float*          h0    = (float*)         (Wp + 50987008);   // [6b-6c] (xpwb/wdtb dead)
    // split-K partials (4 x 6.29 MB):
    float*          part_op = (float*)       (Wp + 0);          // [8a-8b] (hfin/aprod dead)
    float*          part_f2 = (float*)       (Wp + 38404096);   // [11a-11b] (x1 ends 38404096)

    dim3 blk(256);

    // 1. bf16 conversions (all weights + x)
    cvt7_k<<<9816, blk, 0, stream>>>(x, in_proj_w, out_proj_w, ffn_w1, ffn_w2, x_proj_w,
                                     dt_proj_w, xb, wib, wob, wf1b, wf2b, xpwb, wdtb);

    // 2. in_proj: xin f32 + z bf16   [2048,3072] K=768
    gemm_sk<5, 1><<<dim3(48, 16, 1), blk, 0, stream>>>(xb, wib, xin, zbuf, nullptr,
                                                       NROWS, 2 * DI, EMBED, nullptr);

    // 3. conv + silu -> xc f32 + xcb bf16
    conv_silu_k<<<(BATCH * SEQ * DI) / 1024, blk, 0, stream>>>(xin, conv_w, conv_b, xc, xcb);

    // 4. x_proj split-K MFMA + reduce
    xproj_mfma<<<dim3(16, 8), blk, 0, stream>>>(xcb, xpwb, part);
    xproj_reduce<<<640, blk, 0, stream>>>(part, xdbl, xdblb);

    // 5. dt_proj + softplus -> delta f32   [2048,1536] K=64
    gemm_sk<1, 1><<<dim3(24, 16, 1), blk, 0, stream>>>(xdblb, wdtb, delta, nullptr, nullptr,
                                                       NROWS, DI, 64, dt_proj_b);

    // 6. chunked scan (TCH=32)
    scan2_a<<<dim3(DI / DBLK, NCH, BATCH), blk, 0, stream>>>(delta, xc, xdbl, A_log, hfin, aprod);
    scan2_b<<<48, blk, 0, stream>>>(hfin, aprod, h0);
    scan2_c<<<dim3(DI / DBLK, NCH, BATCH), blk, 0, stream>>>(delta, xc, xdbl, A_log, D_param,
                                                             zbuf, h0, ybb);

    // 8. out_proj split-K(4) -> partials; fused reduce+resid+LN1 -> x1 + x1b
    gemm_sk<0, 4><<<dim3(12, 16, 4), blk, 0, stream>>>(ybb, wob, nullptr, nullptr, part_op,
                                                       NROWS, EMBED, DI, nullptr);
    reduce_ln<4, 0><<<NROWS, blk, 0, stream>>>(part_op, x, nullptr, ln1_w, ln1_b, x1, x1b);

    // 10. ffn1 + gelu -> fbf bf16   [2048,3072] K=768
    gemm_sk<3, 1><<<dim3(48, 16, 1), blk, 0, stream>>>(x1b, wf1b, nullptr, fbf, nullptr,
                                                       NROWS, FF, EMBED, ffn_b1);

    // 11. ffn2 split-K(4) -> partials; fused reduce+bias+resid+LN2 -> out
    gemm_sk<0, 4><<<dim3(12, 16, 4), blk, 0, stream>>>(fbf, wf2b, nullptr, nullptr, part_f2,
                                                       NROWS, EMBED, FF, nullptr);
    reduce_ln<4, 1><<<NROWS, blk, 0, stream>>>(part_f2, x1, ffn_b2, ln2_w, ln2_b, out, nullptr);
}

// Round 10
// 205.539 us; speedup vs baseline: 1.1183x; 1.0142x over previous
//
#include <hip/hip_runtime.h>
#include <math.h>

#define EMBED 768
#define DI 1536
#define DSTATE 16
#define DCONV 4
#define DTRANK 48
#define FF 3072
#define BATCH 2
#define SEQ 1024
#define NROWS (BATCH*SEQ)
#define TCH 32
#define NCH (SEQ/TCH)
#define DBLK 64

typedef __bf16 bf16x8 __attribute__((ext_vector_type(8)));
typedef float f32x4 __attribute__((ext_vector_type(4)));
typedef unsigned int u32x4 __attribute__((ext_vector_type(4)));

static __device__ __forceinline__ unsigned short f2b(float f) {
    union { float f; unsigned u; } v; v.f = f;
    unsigned r = v.u + 0x7FFFu + ((v.u >> 16) & 1u);
    return (unsigned short)(r >> 16);
}
static __device__ __forceinline__ float b2f(unsigned short s) {
    union { unsigned u; float f; } v; v.u = ((unsigned)s) << 16;
    return v.f;
}

#define GLOAD_LDS16(g, l) __builtin_amdgcn_global_load_lds( \
    (const __attribute__((address_space(1))) void*)(g), \
    (__attribute__((address_space(3))) void*)(l), 16, 0, 0)

// ---------------------------------------------------------------------------
// gemm_sk: C[M,N] = A[M,K](bf16) @ W[N,K](bf16)^T, 128x64 tile, BK=32,
// 2-phase double-buffered global_load_lds staging (stage next || compute cur,
// one barrier per iter). XOR swizzle on source col + ds_read offset.
// EPI: 1 softplus(acc+bias)->C f32 ; 3 gelu(acc+bias)->Cb bf16 ;
//      6 plain bf16 -> Cb ; KSPLIT>1 -> f32 partials.
// ---------------------------------------------------------------------------
template<int EPI, int KSPLIT>
__global__ __launch_bounds__(256)
void gemm_sk(const unsigned short* __restrict__ A,
             const unsigned short* __restrict__ W,
             float* __restrict__ C, unsigned short* __restrict__ Cb,
             float* __restrict__ part,
             int M, int N, int K,
             const float* __restrict__ bias)
{
    __shared__ alignas(16) unsigned short As[2][128 * 32];   // 2 x 8 KB
    __shared__ alignas(16) unsigned short Ws[2][64 * 32];    // 2 x 4 KB
    const int tid  = threadIdx.x;
    const int lane = tid & 63, wave = tid >> 6;
    const int bm = blockIdx.y * 128, bn = blockIdx.x * 64;
    const int kc = K / KSPLIT;
    const int kz = blockIdx.z * kc;
    const int ln = lane & 15, lg = lane >> 4;

    f32x4 acc[2][4];
    #pragma unroll
    for (int i = 0; i < 2; ++i)
        #pragma unroll
        for (int j = 0; j < 4; ++j)
            acc[i][j] = (f32x4){0.f, 0.f, 0.f, 0.f};

    const int ra = tid >> 2, ca = tid & 3;
    const int cs = (ca * 8) ^ ((ra & 3) << 3);
    const unsigned short* gA0 = A + (size_t)(bm + ra) * K + kz + cs;
    const unsigned short* gA1 = A + (size_t)(bm + ra + 64) * K + kz + cs;
    const unsigned short* gW  = W + (size_t)(bn + ra) * K + kz + cs;

#define STAGE(bf, kk) do { \
        GLOAD_LDS16(gA0 + (kk), &As[bf][wave * 512]); \
        GLOAD_LDS16(gA1 + (kk), &As[bf][2048 + wave * 512]); \
        GLOAD_LDS16(gW  + (kk), &Ws[bf][wave * 512]); \
    } while (0)

    STAGE(0, 0);
    __syncthreads();
    int buf = 0;
    for (int k0 = 0; k0 < kc; k0 += 32) {
        if (k0 + 32 < kc) STAGE(buf ^ 1, k0 + 32);
        bf16x8 af[2], wf[4];
        #pragma unroll
        for (int i = 0; i < 2; ++i) {
            int row = wave * 32 + i * 16 + ln;
            af[i] = *reinterpret_cast<const bf16x8*>(
                &As[buf][row * 32 + ((lg * 8) ^ ((row & 3) << 3))]);
        }
        #pragma unroll
        for (int j = 0; j < 4; ++j) {
            int row = j * 16 + ln;
            wf[j] = *reinterpret_cast<const bf16x8*>(
                &Ws[buf][row * 32 + ((lg * 8) ^ ((row & 3) << 3))]);
        }
        #pragma unroll
        for (int i = 0; i < 2; ++i)
            #pragma unroll
            for (int j = 0; j < 4; ++j)
                acc[i][j] = __builtin_amdgcn_mfma_f32_16x16x32_bf16(af[i], wf[j], acc[i][j], 0, 0, 0);
        __syncthreads();   // drains staged loads for buf^1; protects buf reuse
        buf ^= 1;
    }
#undef STAGE

    if constexpr (KSPLIT > 1) {
        float* pb = part + (size_t)blockIdx.z * M * N;
        #pragma unroll
        for (int i = 0; i < 2; ++i)
            #pragma unroll
            for (int j = 0; j < 4; ++j) {
                int col = bn + j * 16 + ln;
                #pragma unroll
                for (int rr = 0; rr < 4; ++rr) {
                    int row = bm + wave * 32 + i * 16 + lg * 4 + rr;
                    pb[(size_t)row * N + col] = acc[i][j][rr];
                }
            }
    } else {
        #pragma unroll
        for (int i = 0; i < 2; ++i)
            #pragma unroll
            for (int j = 0; j < 4; ++j) {
                int col = bn + j * 16 + ln;
                #pragma unroll
                for (int rr = 0; rr < 4; ++rr) {
                    int row = bm + wave * 32 + i * 16 + lg * 4 + rr;
                    float v = acc[i][j][rr];
                    size_t o = (size_t)row * N + col;
                    if (EPI == 1) {
                        v += bias[col];
                        C[o] = (v > 20.f) ? v : log1pf(expf(v));
                    } else if (EPI == 3) {
                        v += bias[col];
                        float t = 0.7978845608028654f * (v + 0.044715f * v * v * v);
                        Cb[o] = f2b(0.5f * v * (1.f + tanhf(t)));
                    } else if (EPI == 6) {
                        Cb[o] = f2b(v);
                    } else {
                        C[o] = v;
                    }
                }
            }
    }
}

// ---------------------------------------------------------------------------
// reduce_ln: sum KS split-K partials (+bias) (+resid), then LayerNorm(768).
// ---------------------------------------------------------------------------
template<int KS, int BIAS>
__global__ __launch_bounds__(256)
void reduce_ln(const float* __restrict__ part, const float* __restrict__ resid,
               const float* __restrict__ bias,
               const float* __restrict__ w, const float* __restrict__ bb,
               float* __restrict__ out, unsigned short* __restrict__ outb)
{
    const int row = blockIdx.x;
    const size_t ro = (size_t)row * EMBED;
    const int i0 = threadIdx.x, i1 = i0 + 256, i2 = i0 + 512;
    float v0 = 0.f, v1 = 0.f, v2 = 0.f;
    #pragma unroll
    for (int z = 0; z < KS; ++z) {
        const float* p = part + (size_t)z * NROWS * EMBED + ro;
        v0 += p[i0]; v1 += p[i1]; v2 += p[i2];
    }
    if (BIAS) { v0 += bias[i0]; v1 += bias[i1]; v2 += bias[i2]; }
    v0 += resid[ro + i0]; v1 += resid[ro + i1]; v2 += resid[ro + i2];

    float s  = v0 + v1 + v2;
    float s2 = v0 * v0 + v1 * v1 + v2 * v2;
    #pragma unroll
    for (int m = 1; m < 64; m <<= 1) {
        s  += __shfl_xor(s,  m);
        s2 += __shfl_xor(s2, m);
    }
    __shared__ float sh1[4], sh2[4];
    int wv = threadIdx.x >> 6;
    if ((threadIdx.x & 63) == 0) { sh1[wv] = s; sh2[wv] = s2; }
    __syncthreads();
    float S1 = sh1[0] + sh1[1] + sh1[2] + sh1[3];
    float S2 = sh2[0] + sh2[1] + sh2[2] + sh2[3];
    float mu  = S1 * (1.f / EMBED);
    float var = S2 * (1.f / EMBED) - mu * mu;
    float rs  = rsqrtf(var + 1e-5f);
    float o0 = (v0 - mu) * rs * w[i0] + bb[i0];
    float o1 = (v1 - mu) * rs * w[i1] + bb[i1];
    float o2 = (v2 - mu) * rs * w[i2] + bb[i2];
    out[ro + i0] = o0; out[ro + i1] = o1; out[ro + i2] = o2;
    if (outb) {
        outb[ro + i0] = f2b(o0); outb[ro + i1] = f2b(o1); outb[ro + i2] = f2b(o2);
    }
}

// ---------------------------------------------------------------------------
// x_proj split-K MFMA + reduce
// ---------------------------------------------------------------------------
__global__ __launch_bounds__(256)
void xproj_mfma(const unsigned short* __restrict__ A,
                const unsigned short* __restrict__ W,
                float* __restrict__ part)
{
    const int mt = blockIdx.x, s = blockIdx.y;
    const int lane = threadIdx.x & 63, wave = threadIdx.x >> 6;
    const int ln = lane & 15, lg = lane >> 4;
    const int row0 = mt * 128 + wave * 32;
    const int kb = s * 192;
    f32x4 acc[2][5];
    #pragma unroll
    for (int i = 0; i < 2; ++i)
        #pragma unroll
        for (int j = 0; j < 5; ++j)
            acc[i][j] = (f32x4){0.f, 0.f, 0.f, 0.f};

    for (int kk = 0; kk < 192; kk += 32) {
        const int k = kb + kk + lg * 8;
        bf16x8 af[2], wf[5];
        af[0] = *reinterpret_cast<const bf16x8*>(A + (size_t)(row0 + ln) * DI + k);
        af[1] = *reinterpret_cast<const bf16x8*>(A + (size_t)(row0 + 16 + ln) * DI + k);
        #pragma unroll
        for (int j = 0; j < 5; ++j)
            wf[j] = *reinterpret_cast<const bf16x8*>(W + (size_t)(j * 16 + ln) * DI + k);
        #pragma unroll
        for (int i = 0; i < 2; ++i)
            #pragma unroll
            for (int j = 0; j < 5; ++j)
                acc[i][j] = __builtin_amdgcn_mfma_f32_16x16x32_bf16(af[i], wf[j], acc[i][j], 0, 0, 0);
    }
    float* pb = part + (size_t)s * NROWS * 80;
    #pragma unroll
    for (int i = 0; i < 2; ++i)
        #pragma unroll
        for (int j = 0; j < 5; ++j)
            #pragma unroll
            for (int rr = 0; rr < 4; ++rr) {
                int row = row0 + i * 16 + lg * 4 + rr;
                int col = j * 16 + ln;
                pb[(size_t)row * 80 + col] = acc[i][j][rr];
            }
}

__global__ __launch_bounds__(256)
void xproj_reduce(const float* __restrict__ part, float* __restrict__ xdbl,
                  unsigned short* __restrict__ xdblb)
{
    int idx = blockIdx.x * 256 + threadIdx.x;      // 163840
    float sum = 0.f;
    #pragma unroll
    for (int s = 0; s < 8; ++s) sum += part[(size_t)s * NROWS * 80 + idx];
    xdbl[idx] = sum;
    int col = idx % 80, row = idx / 80;
    if (col < 48)      xdblb[row * 64 + col] = f2b(sum);
    else if (col < 64) xdblb[row * 64 + col] = 0;
}

// ---------------------------------------------------------------------------
// f32 -> bf16 conversion: x + 4 big weights + x_proj_w + padded dt_proj_w.
// ---------------------------------------------------------------------------
__global__ __launch_bounds__(256)
void cvt7_k(const float* __restrict__ x,  const float* __restrict__ w1,
            const float* __restrict__ w2, const float* __restrict__ w3,
            const float* __restrict__ w4, const float* __restrict__ w5,
            const float* __restrict__ w6,
            unsigned short* __restrict__ xb,  unsigned short* __restrict__ w1b,
            unsigned short* __restrict__ w2b, unsigned short* __restrict__ w3b,
            unsigned short* __restrict__ w4b, unsigned short* __restrict__ w5b,
            unsigned short* __restrict__ w6b)
{
    size_t i4 = ((size_t)blockIdx.x * 256 + threadIdx.x) * 4;
    if (i4 >= 9953280u) {
        int off = (int)(i4 - 9953280u);
        if (off >= 98304) return;
        int row = off >> 6, colb = off & 63;
        ushort4 u = {0, 0, 0, 0};
        if (colb < 48) {
            float4 v = *reinterpret_cast<const float4*>(w6 + row * 48 + colb);
            u.x = f2b(v.x); u.y = f2b(v.y); u.z = f2b(v.z); u.w = f2b(v.w);
        }
        *reinterpret_cast<ushort4*>(w6b + off) = u;
        return;
    }
    const float* src; unsigned short* dst; size_t off;
    if      (i4 < 1572864u) { src = x;  dst = xb;  off = i4; }
    else if (i4 < 3932160u) { src = w1; dst = w1b; off = i4 - 1572864u; }
    else if (i4 < 5111808u) { src = w2; dst = w2b; off = i4 - 3932160u; }
    else if (i4 < 7471104u) { src = w3; dst = w3b; off = i4 - 5111808u; }
    else if (i4 < 9830400u) { src = w4; dst = w4b; off = i4 - 7471104u; }
    else                    { src = w5; dst = w5b; off = i4 - 9830400u; }
    float4 v = *reinterpret_cast<const float4*>(src + off);
    ushort4 u;
    u.x = f2b(v.x); u.y = f2b(v.y); u.z = f2b(v.z); u.w = f2b(v.w);
    *reinterpret_cast<ushort4*>(dst + off) = u;
}

// ---------------------------------------------------------------------------
// Causal depthwise conv(4) + bias + SiLU; reads bf16 xz (stride 2*DI),
// 4 channels per thread; writes xc f32 + xcb bf16.
// ---------------------------------------------------------------------------
__global__ __launch_bounds__(256)
void conv_silu_k(const unsigned short* __restrict__ xz, const float* __restrict__ cw,
                 const float* __restrict__ cb, float* __restrict__ xc,
                 unsigned short* __restrict__ xcb)
{
    int q = blockIdx.x * 256 + threadIdx.x;
    int d4 = (q * 4) % DI;
    int bt = (q * 4) / DI;
    int t  = bt % SEQ;
    const unsigned short* base = xz + (size_t)bt * (2 * DI) + d4;
    float4 acc = *reinterpret_cast<const float4*>(cb + d4);
    float4 wv0 = *reinterpret_cast<const float4*>(cw + (d4 + 0) * 4);
    float4 wv1 = *reinterpret_cast<const float4*>(cw + (d4 + 1) * 4);
    float4 wv2 = *reinterpret_cast<const float4*>(cw + (d4 + 2) * 4);
    float4 wv3 = *reinterpret_cast<const float4*>(cw + (d4 + 3) * 4);
    {
        ushort4 r = *reinterpret_cast<const ushort4*>(base);
        acc.x += wv0.w * b2f(r.x); acc.y += wv1.w * b2f(r.y);
        acc.z += wv2.w * b2f(r.z); acc.w += wv3.w * b2f(r.w);
    }
    if (t >= 1) {
        ushort4 r = *reinterpret_cast<const ushort4*>(base - 2 * DI);
        acc.x += wv0.z * b2f(r.x); acc.y += wv1.z * b2f(r.y);
        acc.z += wv2.z * b2f(r.z); acc.w += wv3.z * b2f(r.w);
    }
    if (t >= 2) {
        ushort4 r = *reinterpret_cast<const ushort4*>(base - 4 * DI);
        acc.x += wv0.y * b2f(r.x); acc.y += wv1.y * b2f(r.y);
        acc.z += wv2.y * b2f(r.z); acc.w += wv3.y * b2f(r.w);
    }
    if (t >= 3) {
        ushort4 r = *reinterpret_cast<const ushort4*>(base - 6 * DI);
        acc.x += wv0.x * b2f(r.x); acc.y += wv1.x * b2f(r.y);
        acc.z += wv2.x * b2f(r.z); acc.w += wv3.x * b2f(r.w);
    }
    float4 v;
    v.x = acc.x / (1.f + __expf(-acc.x));
    v.y = acc.y / (1.f + __expf(-acc.y));
    v.z = acc.z / (1.f + __expf(-acc.z));
    v.w = acc.w / (1.f + __expf(-acc.w));
    size_t o = (size_t)bt * DI + d4;
    *reinterpret_cast<float4*>(xc + o) = v;
    ushort4 u; u.x = f2b(v.x); u.y = f2b(v.y); u.z = f2b(v.z); u.w = f2b(v.w);
    *reinterpret_cast<ushort4*>(xcb + o) = u;
}

// ---------------------------------------------------------------------------
// scan2_a: per-chunk local scan (TCH=32), n-quad per thread.
// ---------------------------------------------------------------------------
__global__ __launch_bounds__(256)
void scan2_a(const float* __restrict__ delta, const float* __restrict__ xc,
             const float* __restrict__ xdbl,  const float* __restrict__ A_log,
             float* __restrict__ hfin, float* __restrict__ aprod)
{
    const int d0 = blockIdx.x * DBLK, ch = blockIdx.y, b = blockIdx.z;
    const int t0 = ch * TCH;
    __shared__ float del_s[TCH][DBLK + 4];
    __shared__ float xc_s[TCH][DBLK + 4];
    __shared__ float b_s[TCH][20];
    const int tid = threadIdx.x;
    {
        const int c4 = tid & 15, tr = tid >> 4;
        #pragma unroll
        for (int p = 0; p < 2; ++p) {
            int t = p * 16 + tr;
            size_t rowo = (size_t)(b * SEQ + t0 + t);
            *reinterpret_cast<float4*>(&del_s[t][c4 * 4]) =
                *reinterpret_cast<const float4*>(&delta[rowo * DI + d0 + c4 * 4]);
            *reinterpret_cast<float4*>(&xc_s[t][c4 * 4]) =
                *reinterpret_cast<const float4*>(&xc[rowo * DI + d0 + c4 * 4]);
        }
        const int cbq = tid & 3, tb = tid >> 2;
        if (tb < TCH) {
            size_t rowo = (size_t)(b * SEQ + t0 + tb);
            *reinterpret_cast<float4*>(&b_s[tb][cbq * 4]) =
                *reinterpret_cast<const float4*>(&xdbl[rowo * 80 + DTRANK + cbq * 4]);
        }
    }
    __syncthreads();
    const int lane = tid & 63, wave = tid >> 6;
    const int wd = wave * 16 + (lane >> 2);
    const int d = d0 + wd;
    const int nq = (lane & 3) * 4;
    float4 Av = *reinterpret_cast<const float4*>(&A_log[d * DSTATE + nq]);
    const float A0 = -__expf(Av.x), A1 = -__expf(Av.y), A2 = -__expf(Av.z), A3 = -__expf(Av.w);
    float h0_ = 0.f, h1_ = 0.f, h2_ = 0.f, h3_ = 0.f;
    float p0 = 1.f, p1 = 1.f, p2 = 1.f, p3 = 1.f;
    #pragma unroll 4
    for (int t = 0; t < TCH; ++t) {
        float dl = del_s[t][wd];
        float u  = dl * xc_s[t][wd];
        float4 bq = *reinterpret_cast<const float4*>(&b_s[t][nq]);
        float e0 = __expf(dl * A0), e1 = __expf(dl * A1);
        float e2 = __expf(dl * A2), e3 = __expf(dl * A3);
        h0_ = e0 * h0_ + u * bq.x; p0 *= e0;
        h1_ = e1 * h1_ + u * bq.y; p1 *= e1;
        h2_ = e2 * h2_ + u * bq.z; p2 *= e2;
        h3_ = e3 * h3_ + u * bq.w; p3 *= e3;
    }
    size_t o = ((size_t)((b * NCH + ch) * DI) + d) * DSTATE + nq;
    *reinterpret_cast<float4*>(&hfin[o])  = (float4){h0_, h1_, h2_, h3_};
    *reinterpret_cast<float4*>(&aprod[o]) = (float4){p0, p1, p2, p3};
}

// ---------------------------------------------------------------------------
// scan2_b: serial combine over chunks, float4 per thread (one n-quad).
// ---------------------------------------------------------------------------
__global__ __launch_bounds__(256)
void scan2_b(const float* __restrict__ hfin, const float* __restrict__ aprod,
             float* __restrict__ h0)
{
    int idx = blockIdx.x * 256 + threadIdx.x;      // B*DI*4 = 12288
    int nq = (idx & 3) * 4;
    int d  = (idx >> 2) % DI;
    int b  = (idx >> 2) / DI;
    float4 h = {0.f, 0.f, 0.f, 0.f};
    #pragma unroll
    for (int ch = 0; ch < NCH; ++ch) {
        size_t o = ((size_t)((b * NCH + ch) * DI) + d) * DSTATE + nq;
        *reinterpret_cast<float4*>(&h0[o]) = h;
        float4 a = *reinterpret_cast<const float4*>(&aprod[o]);
        float4 f = *reinterpret_cast<const float4*>(&hfin[o]);
        h.x = a.x * h.x + f.x; h.y = a.y * h.y + f.y;
        h.z = a.z * h.z + f.z; h.w = a.w * h.w + f.w;
    }
}

// ---------------------------------------------------------------------------
// scan2_c: full scan from h0 with reduce + gate (TCH=32); z from xz bf16
// (stride 2*DI, offset DI).
// ---------------------------------------------------------------------------
__global__ __launch_bounds__(256)
void scan2_c(const float* __restrict__ delta, const float* __restrict__ xc,
             const float* __restrict__ xdbl,  const float* __restrict__ A_log,
             const float* __restrict__ Dp,    const unsigned short* __restrict__ xz,
             const float* __restrict__ h0,
             unsigned short* __restrict__ yb)
{
    const int d0 = blockIdx.x * DBLK, ch = blockIdx.y, b = blockIdx.z;
    const int t0 = ch * TCH;
    __shared__ float del_s[TCH][DBLK + 4];
    __shared__ float xc_s[TCH][DBLK + 4];
    __shared__ float b_s[TCH][20];
    __shared__ float c_s[TCH][20];
    __shared__ unsigned short z_s[TCH][DBLK + 8];
    const int tid = threadIdx.x;
    {
        const int c4 = tid & 15, tr = tid >> 4;
        #pragma unroll
        for (int p = 0; p < 2; ++p) {
            int t = p * 16 + tr;
            size_t rowo = (size_t)(b * SEQ + t0 + t);
            *reinterpret_cast<float4*>(&del_s[t][c4 * 4]) =
                *reinterpret_cast<const float4*>(&delta[rowo * DI + d0 + c4 * 4]);
            *reinterpret_cast<float4*>(&xc_s[t][c4 * 4]) =
                *reinterpret_cast<const float4*>(&xc[rowo * DI + d0 + c4 * 4]);
        }
        const int cbq = tid & 3, tb = tid >> 2;
        if (tb < TCH) {
            size_t rowo = (size_t)(b * SEQ + t0 + tb);
            *reinterpret_cast<float4*>(&b_s[tb][cbq * 4]) =
                *reinterpret_cast<const float4*>(&xdbl[rowo * 80 + DTRANK + cbq * 4]);
        } else {
            size_t rowo = (size_t)(b * SEQ + t0 + tb - TCH);
            *reinterpret_cast<float4*>(&c_s[tb - TCH][cbq * 4]) =
                *reinterpret_cast<const float4*>(&xdbl[rowo * 80 + DTRANK + DSTATE + cbq * 4]);
        }
        const int cz = tid & 7, tz = tid >> 3;
        size_t rz = (size_t)(b * SEQ + t0 + tz);
        *reinterpret_cast<u32x4*>(&z_s[tz][cz * 8]) =
            *reinterpret_cast<const u32x4*>(&xz[rz * (2 * DI) + DI + d0 + cz * 8]);
    }
    __syncthreads();
    const int lane = tid & 63, wave = tid >> 6;
    const int wd = wave * 16 + (lane >> 2);
    const int d = d0 + wd;
    const int nq = (lane & 3) * 4;
    float4 Av = *reinterpret_cast<const float4*>(&A_log[d * DSTATE + nq]);
    const float A0 = -__expf(Av.x), A1 = -__expf(Av.y), A2 = -__expf(Av.z), A3 = -__expf(Av.w);
    const float Dd = Dp[d];
    float4 h = *reinterpret_cast<const float4*>(
        &h0[((size_t)((b * NCH + ch) * DI) + d) * DSTATE + nq]);
    unsigned short* yrow = yb + (size_t)(b * SEQ + t0) * DI + d;
    #pragma unroll 4
    for (int t = 0; t < TCH; ++t) {
        float dl = del_s[t][wd];
        float xv = xc_s[t][wd];
        float u  = dl * xv;
        float4 bq = *reinterpret_cast<const float4*>(&b_s[t][nq]);
        float4 cq = *reinterpret_cast<const float4*>(&c_s[t][nq]);
        float e0 = __expf(dl * A0), e1 = __expf(dl * A1);
        float e2 = __expf(dl * A2), e3 = __expf(dl * A3);
        h.x = e0 * h.x + u * bq.x;
        h.y = e1 * h.y + u * bq.y;
        h.z = e2 * h.z + u * bq.z;
        h.w = e3 * h.w + u * bq.w;
        float py = h.x * cq.x + h.y * cq.y + h.z * cq.z + h.w * cq.w;
        py += __shfl_xor(py, 1);
        py += __shfl_xor(py, 2);
        if ((lane & 3) == 0) {
            float yv = py + xv * Dd;
            float zv = b2f(z_s[t][wd]);
            yv *= zv / (1.f + __expf(-zv));
            yrow[(size_t)t * DI] = f2b(yv);
        }
    }
}

// ---------------------------------------------------------------------------
extern "C" void kernel_launch(void* const* d_in, const int* in_sizes, int n_in,
                              void* d_out, int out_size, void* d_ws, size_t ws_size,
                              hipStream_t stream)
{
    const float* x         = (const float*)d_in[0];
    const float* in_proj_w = (const float*)d_in[1];
    const float* conv_w    = (const float*)d_in[2];
    const float* conv_b    = (const float*)d_in[3];
    const float* x_proj_w  = (const float*)d_in[4];
    const float* dt_proj_w = (const float*)d_in[5];
    const float* dt_proj_b = (const float*)d_in[6];
    const float* A_log     = (const float*)d_in[7];
    const float* D_param   = (const float*)d_in[8];
    const float* out_proj_w= (const float*)d_in[9];
    const float* ln1_w     = (const float*)d_in[10];
    const float* ln1_b     = (const float*)d_in[11];
    const float* ln2_w     = (const float*)d_in[12];
    const float* ln2_b     = (const float*)d_in[13];
    const float* ffn_w1    = (const float*)d_in[14];
    const float* ffn_b1    = (const float*)d_in[15];
    const float* ffn_w2    = (const float*)d_in[16];
    const float* ffn_b2    = (const float*)d_in[17];
    float* out = (float*)d_out;

    // ws_size = 256 MiB (measured from harness poison fill): disjoint layout.
    char* Wp = (char*)d_ws;
    #define MB(n) ((size_t)(n) * 1048576)
    unsigned short* xzb   = (unsigned short*)(Wp + 0);        // [2048][3072] bf16, 12.6 MB
    float*          xc    = (float*)         (Wp + MB(16));   // 12.6 MB
    unsigned short* xcb   = (unsigned short*)(Wp + MB(30));   // 6.3 MB
    float*          xdbl  = (float*)         (Wp + MB(38));   // 0.66 MB
    unsigned short* xdblb = (unsigned short*)(Wp + MB(40));   // 0.26 MB
    float*          delta = (float*)         (Wp + MB(42));   // 12.6 MB
    unsigned short* ybb   = (unsigned short*)(Wp + MB(56));   // 6.3 MB
    float*          hfin  = (float*)         (Wp + MB(66));   // 6.3 MB
    float*          aprod = (float*)         (Wp + MB(76));   // 6.3 MB
    float*          h0    = (float*)         (Wp + MB(86));   // 6.3 MB
    unsigned short* xb    = (unsigned short*)(Wp + MB(92));   // 3.1 MB
    unsigned short* wib   = (unsigned short*)(Wp + MB(96));   // 4.7 MB
    unsigned short* wob   = (unsigned short*)(Wp + MB(101));  // 2.4 MB
    unsigned short* wf1b  = (unsigned short*)(Wp + MB(104));  // 4.7 MB
    unsigned short* wf2b  = (unsigned short*)(Wp + MB(109));  // 4.7 MB
    unsigned short* xpwb  = (unsigned short*)(Wp + MB(114));  // 0.25 MB
    unsigned short* wdtb  = (unsigned short*)(Wp + MB(115));  // 0.19 MB
    float*          part  = (float*)         (Wp + MB(116));  // 5.3 MB
    float*          part_op = (float*)       (Wp + MB(122));  // 25.2 MB
    float*          part_f2 = (float*)       (Wp + MB(148));  // 25.2 MB
    float*          x1    = (float*)         (Wp + MB(174));  // 6.3 MB
    unsigned short* x1b   = (unsigned short*)(Wp + MB(181));  // 3.1 MB
    unsigned short* fbf   = (unsigned short*)(Wp + MB(185));  // 12.6 MB
    #undef MB

    dim3 blk(256);

    // 1. bf16 conversions (x + all weights)
    cvt7_k<<<9816, blk, 0, stream>>>(x, in_proj_w, out_proj_w, ffn_w1, ffn_w2, x_proj_w,
                                     dt_proj_w, xb, wib, wob, wf1b, wf2b, xpwb, wdtb);

    // 2. in_proj -> xzb bf16 [2048][3072] (xin cols 0..DI-1, z cols DI..)
    gemm_sk<6, 1><<<dim3(48, 16, 1), blk, 0, stream>>>(xb, wib, nullptr, xzb, nullptr,
                                                       NROWS, 2 * DI, EMBED, nullptr);

    // 3. conv + silu -> xc f32 + xcb bf16
    conv_silu_k<<<(BATCH * SEQ * DI) / 1024, blk, 0, stream>>>(xzb, conv_w, conv_b, xc, xcb);

    // 4. x_proj split-K MFMA + reduce
    xproj_mfma<<<dim3(16, 8), blk, 0, stream>>>(xcb, xpwb, part);
    xproj_reduce<<<640, blk, 0, stream>>>(part, xdbl, xdblb);

    // 5. dt_proj + softplus -> delta f32   [2048,1536] K=64
    gemm_sk<1, 1><<<dim3(24, 16, 1), blk, 0, stream>>>(xdblb, wdtb, delta, nullptr, nullptr,
                                                       NROWS, DI, 64, dt_proj_b);

    // 6. chunked scan (TCH=32)
    scan2_a<<<dim3(DI / DBLK, NCH, BATCH), blk, 0, stream>>>(delta, xc, xdbl, A_log, hfin, aprod);
    scan2_b<<<48, blk, 0, stream>>>(hfin, aprod, h0);
    scan2_c<<<dim3(DI / DBLK, NCH, BATCH), blk, 0, stream>>>(delta, xc, xdbl, A_log, D_param,
                                                             xzb, h0, ybb);

    // 8. out_proj split-K(4) -> partials; fused reduce+resid+LN1 -> x1 + x1b
    gemm_sk<0, 4><<<dim3(12, 16, 4), blk, 0, stream>>>(ybb, wob, nullptr, nullptr, part_op,
                                                       NROWS, EMBED, DI, nullptr);
    reduce_ln<4, 0><<<NROWS, blk, 0, stream>>>(part_op, x, nullptr, ln1_w, ln1_b, x1, x1b);

    // 10. ffn1 + gelu -> fbf bf16   [2048,3072] K=768
    gemm_sk<3, 1><<<dim3(48, 16, 1), blk, 0, stream>>>(x1b, wf1b, nullptr, fbf, nullptr,
                                                       NROWS, FF, EMBED, ffn_b1);

    // 11. ffn2 split-K(4) -> partials; fused reduce+bias+resid+LN2 -> out
    gemm_sk<0, 4><<<dim3(12, 16, 4), blk, 0, stream>>>(fbf, wf2b, nullptr, nullptr, part_f2,
                                                       NROWS, EMBED, FF, nullptr);
    reduce_ln<4, 1><<<NROWS, blk, 0, stream>>>(part_f2, x1, ffn_b2, ln2_w, ln2_b, out, nullptr);
}

// Round 11
// 201.532 us; speedup vs baseline: 1.1406x; 1.0199x over previous
//
#include <hip/hip_runtime.h>
#include <math.h>

#define EMBED 768
#define DI 1536
#define DSTATE 16
#define DCONV 4
#define DTRANK 48
#define FF 3072
#define BATCH 2
#define SEQ 1024
#define NROWS (BATCH*SEQ)
#define TCH 32
#define NCH (SEQ/TCH)
#define DBLK 64

typedef __bf16 bf16x8 __attribute__((ext_vector_type(8)));
typedef float f32x4 __attribute__((ext_vector_type(4)));
typedef unsigned int u32x4 __attribute__((ext_vector_type(4)));

static __device__ __forceinline__ unsigned short f2b(float f) {
    union { float f; unsigned u; } v; v.f = f;
    unsigned r = v.u + 0x7FFFu + ((v.u >> 16) & 1u);
    return (unsigned short)(r >> 16);
}
static __device__ __forceinline__ float b2f(unsigned short s) {
    union { unsigned u; float f; } v; v.u = ((unsigned)s) << 16;
    return v.f;
}

#define GLOAD_LDS16(g, l) __builtin_amdgcn_global_load_lds( \
    (const __attribute__((address_space(1))) void*)(g), \
    (__attribute__((address_space(3))) void*)(l), 16, 0, 0)

// ---------------------------------------------------------------------------
// gemm_sk: C[M,N] = A[M,K](bf16) @ W[N,K](bf16)^T, 128x64 tile, BK=32,
// 2-phase double-buffered global_load_lds staging.
// EPI: 1 softplus(acc+bias)->C f32 ; 3 gelu(acc+bias)->Cb bf16 ;
//      6 plain bf16 -> Cb ; KSPLIT>1 -> f32 partials.
// ---------------------------------------------------------------------------
template<int EPI, int KSPLIT>
__global__ __launch_bounds__(256)
void gemm_sk(const unsigned short* __restrict__ A,
             const unsigned short* __restrict__ W,
             float* __restrict__ C, unsigned short* __restrict__ Cb,
             float* __restrict__ part,
             int M, int N, int K,
             const float* __restrict__ bias)
{
    __shared__ alignas(16) unsigned short As[2][128 * 32];
    __shared__ alignas(16) unsigned short Ws[2][64 * 32];
    const int tid  = threadIdx.x;
    const int lane = tid & 63, wave = tid >> 6;
    const int bm = blockIdx.y * 128, bn = blockIdx.x * 64;
    const int kc = K / KSPLIT;
    const int kz = blockIdx.z * kc;
    const int ln = lane & 15, lg = lane >> 4;

    f32x4 acc[2][4];
    #pragma unroll
    for (int i = 0; i < 2; ++i)
        #pragma unroll
        for (int j = 0; j < 4; ++j)
            acc[i][j] = (f32x4){0.f, 0.f, 0.f, 0.f};

    const int ra = tid >> 2, ca = tid & 3;
    const int cs = (ca * 8) ^ ((ra & 3) << 3);
    const unsigned short* gA0 = A + (size_t)(bm + ra) * K + kz + cs;
    const unsigned short* gA1 = A + (size_t)(bm + ra + 64) * K + kz + cs;
    const unsigned short* gW  = W + (size_t)(bn + ra) * K + kz + cs;

#define STAGE(bf, kk) do { \
        GLOAD_LDS16(gA0 + (kk), &As[bf][wave * 512]); \
        GLOAD_LDS16(gA1 + (kk), &As[bf][2048 + wave * 512]); \
        GLOAD_LDS16(gW  + (kk), &Ws[bf][wave * 512]); \
    } while (0)

    STAGE(0, 0);
    __syncthreads();
    int buf = 0;
    for (int k0 = 0; k0 < kc; k0 += 32) {
        if (k0 + 32 < kc) STAGE(buf ^ 1, k0 + 32);
        bf16x8 af[2], wf[4];
        #pragma unroll
        for (int i = 0; i < 2; ++i) {
            int row = wave * 32 + i * 16 + ln;
            af[i] = *reinterpret_cast<const bf16x8*>(
                &As[buf][row * 32 + ((lg * 8) ^ ((row & 3) << 3))]);
        }
        #pragma unroll
        for (int j = 0; j < 4; ++j) {
            int row = j * 16 + ln;
            wf[j] = *reinterpret_cast<const bf16x8*>(
                &Ws[buf][row * 32 + ((lg * 8) ^ ((row & 3) << 3))]);
        }
        #pragma unroll
        for (int i = 0; i < 2; ++i)
            #pragma unroll
            for (int j = 0; j < 4; ++j)
                acc[i][j] = __builtin_amdgcn_mfma_f32_16x16x32_bf16(af[i], wf[j], acc[i][j], 0, 0, 0);
        __syncthreads();
        buf ^= 1;
    }
#undef STAGE

    if constexpr (KSPLIT > 1) {
        float* pb = part + (size_t)blockIdx.z * M * N;
        #pragma unroll
        for (int i = 0; i < 2; ++i)
            #pragma unroll
            for (int j = 0; j < 4; ++j) {
                int col = bn + j * 16 + ln;
                #pragma unroll
                for (int rr = 0; rr < 4; ++rr) {
                    int row = bm + wave * 32 + i * 16 + lg * 4 + rr;
                    pb[(size_t)row * N + col] = acc[i][j][rr];
                }
            }
    } else {
        #pragma unroll
        for (int i = 0; i < 2; ++i)
            #pragma unroll
            for (int j = 0; j < 4; ++j) {
                int col = bn + j * 16 + ln;
                #pragma unroll
                for (int rr = 0; rr < 4; ++rr) {
                    int row = bm + wave * 32 + i * 16 + lg * 4 + rr;
                    float v = acc[i][j][rr];
                    size_t o = (size_t)row * N + col;
                    if (EPI == 1) {
                        v += bias[col];
                        C[o] = (v > 20.f) ? v : log1pf(expf(v));
                    } else if (EPI == 3) {
                        v += bias[col];
                        float t = 0.7978845608028654f * (v + 0.044715f * v * v * v);
                        Cb[o] = f2b(0.5f * v * (1.f + tanhf(t)));
                    } else if (EPI == 6) {
                        Cb[o] = f2b(v);
                    } else {
                        C[o] = v;
                    }
                }
            }
    }
}

// ---------------------------------------------------------------------------
// reduce_ln: sum KS split-K partials (+bias) (+resid), then LayerNorm(768).
// ---------------------------------------------------------------------------
template<int KS, int BIAS>
__global__ __launch_bounds__(256)
void reduce_ln(const float* __restrict__ part, const float* __restrict__ resid,
               const float* __restrict__ bias,
               const float* __restrict__ w, const float* __restrict__ bb,
               float* __restrict__ out, unsigned short* __restrict__ outb)
{
    const int row = blockIdx.x;
    const size_t ro = (size_t)row * EMBED;
    const int i0 = threadIdx.x, i1 = i0 + 256, i2 = i0 + 512;
    float v0 = 0.f, v1 = 0.f, v2 = 0.f;
    #pragma unroll
    for (int z = 0; z < KS; ++z) {
        const float* p = part + (size_t)z * NROWS * EMBED + ro;
        v0 += p[i0]; v1 += p[i1]; v2 += p[i2];
    }
    if (BIAS) { v0 += bias[i0]; v1 += bias[i1]; v2 += bias[i2]; }
    v0 += resid[ro + i0]; v1 += resid[ro + i1]; v2 += resid[ro + i2];

    float s  = v0 + v1 + v2;
    float s2 = v0 * v0 + v1 * v1 + v2 * v2;
    #pragma unroll
    for (int m = 1; m < 64; m <<= 1) {
        s  += __shfl_xor(s,  m);
        s2 += __shfl_xor(s2, m);
    }
    __shared__ float sh1[4], sh2[4];
    int wv = threadIdx.x >> 6;
    if ((threadIdx.x & 63) == 0) { sh1[wv] = s; sh2[wv] = s2; }
    __syncthreads();
    float S1 = sh1[0] + sh1[1] + sh1[2] + sh1[3];
    float S2 = sh2[0] + sh2[1] + sh2[2] + sh2[3];
    float mu  = S1 * (1.f / EMBED);
    float var = S2 * (1.f / EMBED) - mu * mu;
    float rs  = rsqrtf(var + 1e-5f);
    float o0 = (v0 - mu) * rs * w[i0] + bb[i0];
    float o1 = (v1 - mu) * rs * w[i1] + bb[i1];
    float o2 = (v2 - mu) * rs * w[i2] + bb[i2];
    out[ro + i0] = o0; out[ro + i1] = o1; out[ro + i2] = o2;
    if (outb) {
        outb[ro + i0] = f2b(o0); outb[ro + i1] = f2b(o1); outb[ro + i2] = f2b(o2);
    }
}

// ---------------------------------------------------------------------------
// x_proj split-K MFMA + reduce
// ---------------------------------------------------------------------------
__global__ __launch_bounds__(256)
void xproj_mfma(const unsigned short* __restrict__ A,
                const unsigned short* __restrict__ W,
                float* __restrict__ part)
{
    const int mt = blockIdx.x, s = blockIdx.y;
    const int lane = threadIdx.x & 63, wave = threadIdx.x >> 6;
    const int ln = lane & 15, lg = lane >> 4;
    const int row0 = mt * 128 + wave * 32;
    const int kb = s * 192;
    f32x4 acc[2][5];
    #pragma unroll
    for (int i = 0; i < 2; ++i)
        #pragma unroll
        for (int j = 0; j < 5; ++j)
            acc[i][j] = (f32x4){0.f, 0.f, 0.f, 0.f};

    for (int kk = 0; kk < 192; kk += 32) {
        const int k = kb + kk + lg * 8;
        bf16x8 af[2], wf[5];
        af[0] = *reinterpret_cast<const bf16x8*>(A + (size_t)(row0 + ln) * DI + k);
        af[1] = *reinterpret_cast<const bf16x8*>(A + (size_t)(row0 + 16 + ln) * DI + k);
        #pragma unroll
        for (int j = 0; j < 5; ++j)
            wf[j] = *reinterpret_cast<const bf16x8*>(W + (size_t)(j * 16 + ln) * DI + k);
        #pragma unroll
        for (int i = 0; i < 2; ++i)
            #pragma unroll
            for (int j = 0; j < 5; ++j)
                acc[i][j] = __builtin_amdgcn_mfma_f32_16x16x32_bf16(af[i], wf[j], acc[i][j], 0, 0, 0);
    }
    float* pb = part + (size_t)s * NROWS * 80;
    #pragma unroll
    for (int i = 0; i < 2; ++i)
        #pragma unroll
        for (int j = 0; j < 5; ++j)
            #pragma unroll
            for (int rr = 0; rr < 4; ++rr) {
                int row = row0 + i * 16 + lg * 4 + rr;
                int col = j * 16 + ln;
                pb[(size_t)row * 80 + col] = acc[i][j][rr];
            }
}

__global__ __launch_bounds__(256)
void xproj_reduce(const float* __restrict__ part, float* __restrict__ xdbl,
                  unsigned short* __restrict__ xdblb)
{
    int idx = blockIdx.x * 256 + threadIdx.x;      // 163840
    float sum = 0.f;
    #pragma unroll
    for (int s = 0; s < 8; ++s) sum += part[(size_t)s * NROWS * 80 + idx];
    xdbl[idx] = sum;
    int col = idx % 80, row = idx / 80;
    if (col < 48)      xdblb[row * 64 + col] = f2b(sum);
    else if (col < 64) xdblb[row * 64 + col] = 0;
}

// ---------------------------------------------------------------------------
// f32 -> bf16 conversion: x + 4 big weights + x_proj_w + padded dt_proj_w.
// ---------------------------------------------------------------------------
__global__ __launch_bounds__(256)
void cvt7_k(const float* __restrict__ x,  const float* __restrict__ w1,
            const float* __restrict__ w2, const float* __restrict__ w3,
            const float* __restrict__ w4, const float* __restrict__ w5,
            const float* __restrict__ w6,
            unsigned short* __restrict__ xb,  unsigned short* __restrict__ w1b,
            unsigned short* __restrict__ w2b, unsigned short* __restrict__ w3b,
            unsigned short* __restrict__ w4b, unsigned short* __restrict__ w5b,
            unsigned short* __restrict__ w6b)
{
    size_t i4 = ((size_t)blockIdx.x * 256 + threadIdx.x) * 4;
    if (i4 >= 9953280u) {
        int off = (int)(i4 - 9953280u);
        if (off >= 98304) return;
        int row = off >> 6, colb = off & 63;
        ushort4 u = {0, 0, 0, 0};
        if (colb < 48) {
            float4 v = *reinterpret_cast<const float4*>(w6 + row * 48 + colb);
            u.x = f2b(v.x); u.y = f2b(v.y); u.z = f2b(v.z); u.w = f2b(v.w);
        }
        *reinterpret_cast<ushort4*>(w6b + off) = u;
        return;
    }
    const float* src; unsigned short* dst; size_t off;
    if      (i4 < 1572864u) { src = x;  dst = xb;  off = i4; }
    else if (i4 < 3932160u) { src = w1; dst = w1b; off = i4 - 1572864u; }
    else if (i4 < 5111808u) { src = w2; dst = w2b; off = i4 - 3932160u; }
    else if (i4 < 7471104u) { src = w3; dst = w3b; off = i4 - 5111808u; }
    else if (i4 < 9830400u) { src = w4; dst = w4b; off = i4 - 7471104u; }
    else                    { src = w5; dst = w5b; off = i4 - 9830400u; }
    float4 v = *reinterpret_cast<const float4*>(src + off);
    ushort4 u;
    u.x = f2b(v.x); u.y = f2b(v.y); u.z = f2b(v.z); u.w = f2b(v.w);
    *reinterpret_cast<ushort4*>(dst + off) = u;
}

// ---------------------------------------------------------------------------
// Causal depthwise conv(4) + bias + SiLU; reads bf16 xz (stride 2*DI),
// 4 channels per thread; writes xcb bf16 only.
// ---------------------------------------------------------------------------
__global__ __launch_bounds__(256)
void conv_silu_k(const unsigned short* __restrict__ xz, const float* __restrict__ cw,
                 const float* __restrict__ cb, unsigned short* __restrict__ xcb)
{
    int q = blockIdx.x * 256 + threadIdx.x;
    int d4 = (q * 4) % DI;
    int bt = (q * 4) / DI;
    int t  = bt % SEQ;
    const unsigned short* base = xz + (size_t)bt * (2 * DI) + d4;
    float4 acc = *reinterpret_cast<const float4*>(cb + d4);
    float4 wv0 = *reinterpret_cast<const float4*>(cw + (d4 + 0) * 4);
    float4 wv1 = *reinterpret_cast<const float4*>(cw + (d4 + 1) * 4);
    float4 wv2 = *reinterpret_cast<const float4*>(cw + (d4 + 2) * 4);
    float4 wv3 = *reinterpret_cast<const float4*>(cw + (d4 + 3) * 4);
    {
        ushort4 r = *reinterpret_cast<const ushort4*>(base);
        acc.x += wv0.w * b2f(r.x); acc.y += wv1.w * b2f(r.y);
        acc.z += wv2.w * b2f(r.z); acc.w += wv3.w * b2f(r.w);
    }
    if (t >= 1) {
        ushort4 r = *reinterpret_cast<const ushort4*>(base - 2 * DI);
        acc.x += wv0.z * b2f(r.x); acc.y += wv1.z * b2f(r.y);
        acc.z += wv2.z * b2f(r.z); acc.w += wv3.z * b2f(r.w);
    }
    if (t >= 2) {
        ushort4 r = *reinterpret_cast<const ushort4*>(base - 4 * DI);
        acc.x += wv0.y * b2f(r.x); acc.y += wv1.y * b2f(r.y);
        acc.z += wv2.y * b2f(r.z); acc.w += wv3.y * b2f(r.w);
    }
    if (t >= 3) {
        ushort4 r = *reinterpret_cast<const ushort4*>(base - 6 * DI);
        acc.x += wv0.x * b2f(r.x); acc.y += wv1.x * b2f(r.y);
        acc.z += wv2.x * b2f(r.z); acc.w += wv3.x * b2f(r.w);
    }
    ushort4 u;
    u.x = f2b(acc.x / (1.f + __expf(-acc.x)));
    u.y = f2b(acc.y / (1.f + __expf(-acc.y)));
    u.z = f2b(acc.z / (1.f + __expf(-acc.z)));
    u.w = f2b(acc.w / (1.f + __expf(-acc.w)));
    *reinterpret_cast<ushort4*>(xcb + (size_t)bt * DI + d4) = u;
}

// ---------------------------------------------------------------------------
// scan2_a: per-chunk local scan (TCH=32), n-quad per thread; xc from bf16.
// ---------------------------------------------------------------------------
__global__ __launch_bounds__(256)
void scan2_a(const float* __restrict__ delta, const unsigned short* __restrict__ xcb,
             const float* __restrict__ xdbl,  const float* __restrict__ A_log,
             float* __restrict__ hfin, float* __restrict__ aprod)
{
    const int d0 = blockIdx.x * DBLK, ch = blockIdx.y, b = blockIdx.z;
    const int t0 = ch * TCH;
    __shared__ float del_s[TCH][DBLK + 4];
    __shared__ unsigned short xc_s[TCH][DBLK + 8];
    __shared__ float b_s[TCH][20];
    const int tid = threadIdx.x;
    {
        const int c4 = tid & 15, tr = tid >> 4;
        #pragma unroll
        for (int p = 0; p < 2; ++p) {
            int t = p * 16 + tr;
            size_t rowo = (size_t)(b * SEQ + t0 + t);
            *reinterpret_cast<float4*>(&del_s[t][c4 * 4]) =
                *reinterpret_cast<const float4*>(&delta[rowo * DI + d0 + c4 * 4]);
        }
        const int cz = tid & 7, tz = tid >> 3;
        size_t rz = (size_t)(b * SEQ + t0 + tz);
        *reinterpret_cast<u32x4*>(&xc_s[tz][cz * 8]) =
            *reinterpret_cast<const u32x4*>(&xcb[rz * DI + d0 + cz * 8]);
        const int cbq = tid & 3, tb = tid >> 2;
        if (tb < TCH) {
            size_t rowo = (size_t)(b * SEQ + t0 + tb);
            *reinterpret_cast<float4*>(&b_s[tb][cbq * 4]) =
                *reinterpret_cast<const float4*>(&xdbl[rowo * 80 + DTRANK + cbq * 4]);
        }
    }
    __syncthreads();
    const int lane = tid & 63, wave = tid >> 6;
    const int wd = wave * 16 + (lane >> 2);
    const int d = d0 + wd;
    const int nq = (lane & 3) * 4;
    float4 Av = *reinterpret_cast<const float4*>(&A_log[d * DSTATE + nq]);
    const float A0 = -__expf(Av.x), A1 = -__expf(Av.y), A2 = -__expf(Av.z), A3 = -__expf(Av.w);
    float h0_ = 0.f, h1_ = 0.f, h2_ = 0.f, h3_ = 0.f;
    float p0 = 1.f, p1 = 1.f, p2 = 1.f, p3 = 1.f;
    #pragma unroll 4
    for (int t = 0; t < TCH; ++t) {
        float dl = del_s[t][wd];
        float u  = dl * b2f(xc_s[t][wd]);
        float4 bq = *reinterpret_cast<const float4*>(&b_s[t][nq]);
        float e0 = __expf(dl * A0), e1 = __expf(dl * A1);
        float e2 = __expf(dl * A2), e3 = __expf(dl * A3);
        h0_ = e0 * h0_ + u * bq.x; p0 *= e0;
        h1_ = e1 * h1_ + u * bq.y; p1 *= e1;
        h2_ = e2 * h2_ + u * bq.z; p2 *= e2;
        h3_ = e3 * h3_ + u * bq.w; p3 *= e3;
    }
    size_t o = ((size_t)((b * NCH + ch) * DI) + d) * DSTATE + nq;
    *reinterpret_cast<float4*>(&hfin[o])  = (float4){h0_, h1_, h2_, h3_};
    *reinterpret_cast<float4*>(&aprod[o]) = (float4){p0, p1, p2, p3};
}

// ---------------------------------------------------------------------------
// scan2_c: in-kernel chunk-prefix + full scan + reduce + gate (TCH=32).
// xc from bf16; z from xz bf16 (stride 2*DI, offset DI).
// ---------------------------------------------------------------------------
__global__ __launch_bounds__(256)
void scan2_c(const float* __restrict__ delta, const unsigned short* __restrict__ xcb,
             const float* __restrict__ xdbl,  const float* __restrict__ A_log,
             const float* __restrict__ Dp,    const unsigned short* __restrict__ xz,
             const float* __restrict__ hfin,  const float* __restrict__ aprod,
             unsigned short* __restrict__ yb)
{
    const int d0 = blockIdx.x * DBLK, ch = blockIdx.y, b = blockIdx.z;
    const int t0 = ch * TCH;
    __shared__ float del_s[TCH][DBLK + 4];
    __shared__ unsigned short xc_s[TCH][DBLK + 8];
    __shared__ float b_s[TCH][20];
    __shared__ float c_s[TCH][20];
    __shared__ unsigned short z_s[TCH][DBLK + 8];
    const int tid = threadIdx.x;
    {
        const int c4 = tid & 15, tr = tid >> 4;
        #pragma unroll
        for (int p = 0; p < 2; ++p) {
            int t = p * 16 + tr;
            size_t rowo = (size_t)(b * SEQ + t0 + t);
            *reinterpret_cast<float4*>(&del_s[t][c4 * 4]) =
                *reinterpret_cast<const float4*>(&delta[rowo * DI + d0 + c4 * 4]);
        }
        const int cz = tid & 7, tz = tid >> 3;
        size_t rz = (size_t)(b * SEQ + t0 + tz);
        *reinterpret_cast<u32x4*>(&xc_s[tz][cz * 8]) =
            *reinterpret_cast<const u32x4*>(&xcb[rz * DI + d0 + cz * 8]);
        *reinterpret_cast<u32x4*>(&z_s[tz][cz * 8]) =
            *reinterpret_cast<const u32x4*>(&xz[rz * (2 * DI) + DI + d0 + cz * 8]);
        const int cbq = tid & 3, tb = tid >> 2;
        if (tb < TCH) {
            size_t rowo = (size_t)(b * SEQ + t0 + tb);
            *reinterpret_cast<float4*>(&b_s[tb][cbq * 4]) =
                *reinterpret_cast<const float4*>(&xdbl[rowo * 80 + DTRANK + cbq * 4]);
        } else {
            size_t rowo = (size_t)(b * SEQ + t0 + tb - TCH);
            *reinterpret_cast<float4*>(&c_s[tb - TCH][cbq * 4]) =
                *reinterpret_cast<const float4*>(&xdbl[rowo * 80 + DTRANK + DSTATE + cbq * 4]);
        }
    }
    const int lane = tid & 63, wave = tid >> 6;
    const int wd = wave * 16 + (lane >> 2);
    const int d = d0 + wd;
    const int nq = (lane & 3) * 4;

    // chunk-prefix recombine (address-independent loads; overlaps staging)
    float4 h = {0.f, 0.f, 0.f, 0.f};
    for (int cc = 0; cc < ch; ++cc) {
        size_t o = ((size_t)((b * NCH + cc) * DI) + d) * DSTATE + nq;
        float4 a = *reinterpret_cast<const float4*>(&aprod[o]);
        float4 f = *reinterpret_cast<const float4*>(&hfin[o]);
        h.x = a.x * h.x + f.x; h.y = a.y * h.y + f.y;
        h.z = a.z * h.z + f.z; h.w = a.w * h.w + f.w;
    }

    float4 Av = *reinterpret_cast<const float4*>(&A_log[d * DSTATE + nq]);
    const float A0 = -__expf(Av.x), A1 = -__expf(Av.y), A2 = -__expf(Av.z), A3 = -__expf(Av.w);
    const float Dd = Dp[d];
    __syncthreads();
    unsigned short* yrow = yb + (size_t)(b * SEQ + t0) * DI + d;
    #pragma unroll 4
    for (int t = 0; t < TCH; ++t) {
        float dl = del_s[t][wd];
        float xv = b2f(xc_s[t][wd]);
        float u  = dl * xv;
        float4 bq = *reinterpret_cast<const float4*>(&b_s[t][nq]);
        float4 cq = *reinterpret_cast<const float4*>(&c_s[t][nq]);
        float e0 = __expf(dl * A0), e1 = __expf(dl * A1);
        float e2 = __expf(dl * A2), e3 = __expf(dl * A3);
        h.x = e0 * h.x + u * bq.x;
        h.y = e1 * h.y + u * bq.y;
        h.z = e2 * h.z + u * bq.z;
        h.w = e3 * h.w + u * bq.w;
        float py = h.x * cq.x + h.y * cq.y + h.z * cq.z + h.w * cq.w;
        py += __shfl_xor(py, 1);
        py += __shfl_xor(py, 2);
        if ((lane & 3) == 0) {
            float yv = py + xv * Dd;
            float zv = b2f(z_s[t][wd]);
            yv *= zv / (1.f + __expf(-zv));
            yrow[(size_t)t * DI] = f2b(yv);
        }
    }
}

// ---------------------------------------------------------------------------
extern "C" void kernel_launch(void* const* d_in, const int* in_sizes, int n_in,
                              void* d_out, int out_size, void* d_ws, size_t ws_size,
                              hipStream_t stream)
{
    const float* x         = (const float*)d_in[0];
    const float* in_proj_w = (const float*)d_in[1];
    const float* conv_w    = (const float*)d_in[2];
    const float* conv_b    = (const float*)d_in[3];
    const float* x_proj_w  = (const float*)d_in[4];
    const float* dt_proj_w = (const float*)d_in[5];
    const float* dt_proj_b = (const float*)d_in[6];
    const float* A_log     = (const float*)d_in[7];
    const float* D_param   = (const float*)d_in[8];
    const float* out_proj_w= (const float*)d_in[9];
    const float* ln1_w     = (const float*)d_in[10];
    const float* ln1_b     = (const float*)d_in[11];
    const float* ln2_w     = (const float*)d_in[12];
    const float* ln2_b     = (const float*)d_in[13];
    const float* ffn_w1    = (const float*)d_in[14];
    const float* ffn_b1    = (const float*)d_in[15];
    const float* ffn_w2    = (const float*)d_in[16];
    const float* ffn_b2    = (const float*)d_in[17];
    float* out = (float*)d_out;

    char* Wp = (char*)d_ws;
    #define MB(n) ((size_t)(n) * 1048576)
    unsigned short* xzb   = (unsigned short*)(Wp + 0);        // 12.6 MB
    unsigned short* xcb   = (unsigned short*)(Wp + MB(16));   // 6.3 MB
    float*          xdbl  = (float*)         (Wp + MB(24));   // 0.66 MB
    unsigned short* xdblb = (unsigned short*)(Wp + MB(26));   // 0.26 MB
    float*          delta = (float*)         (Wp + MB(28));   // 12.6 MB
    unsigned short* ybb   = (unsigned short*)(Wp + MB(42));   // 6.3 MB
    float*          hfin  = (float*)         (Wp + MB(50));   // 6.3 MB
    float*          aprod = (float*)         (Wp + MB(58));   // 6.3 MB
    unsigned short* xb    = (unsigned short*)(Wp + MB(66));   // 3.1 MB
    unsigned short* wib   = (unsigned short*)(Wp + MB(70));   // 4.7 MB
    unsigned short* wob   = (unsigned short*)(Wp + MB(75));   // 2.4 MB
    unsigned short* wf1b  = (unsigned short*)(Wp + MB(78));   // 4.7 MB
    unsigned short* wf2b  = (unsigned short*)(Wp + MB(83));   // 4.7 MB
    unsigned short* xpwb  = (unsigned short*)(Wp + MB(88));   // 0.25 MB
    unsigned short* wdtb  = (unsigned short*)(Wp + MB(89));   // 0.19 MB
    float*          part  = (float*)         (Wp + MB(90));   // 5.3 MB
    float*          part_op = (float*)       (Wp + MB(96));   // 25.2 MB
    float*          part_f2 = (float*)       (Wp + MB(122));  // 25.2 MB
    float*          x1    = (float*)         (Wp + MB(148));  // 6.3 MB
    unsigned short* x1b   = (unsigned short*)(Wp + MB(155));  // 3.1 MB
    unsigned short* fbf   = (unsigned short*)(Wp + MB(159));  // 12.6 MB
    #undef MB

    dim3 blk(256);

    // 1. bf16 conversions (x + all weights)
    cvt7_k<<<9816, blk, 0, stream>>>(x, in_proj_w, out_proj_w, ffn_w1, ffn_w2, x_proj_w,
                                     dt_proj_w, xb, wib, wob, wf1b, wf2b, xpwb, wdtb);

    // 2. in_proj -> xzb bf16 [2048][3072]
    gemm_sk<6, 1><<<dim3(48, 16, 1), blk, 0, stream>>>(xb, wib, nullptr, xzb, nullptr,
                                                       NROWS, 2 * DI, EMBED, nullptr);

    // 3. conv + silu -> xcb bf16
    conv_silu_k<<<(BATCH * SEQ * DI) / 1024, blk, 0, stream>>>(xzb, conv_w, conv_b, xcb);

    // 4. x_proj split-K MFMA + reduce
    xproj_mfma<<<dim3(16, 8), blk, 0, stream>>>(xcb, xpwb, part);
    xproj_reduce<<<640, blk, 0, stream>>>(part, xdbl, xdblb);

    // 5. dt_proj + softplus -> delta f32
    gemm_sk<1, 1><<<dim3(24, 16, 1), blk, 0, stream>>>(xdblb, wdtb, delta, nullptr, nullptr,
                                                       NROWS, DI, 64, dt_proj_b);

    // 6. chunked scan (TCH=32): local scans, then prefix+finish (b folded in c)
    scan2_a<<<dim3(DI / DBLK, NCH, BATCH), blk, 0, stream>>>(delta, xcb, xdbl, A_log, hfin, aprod);
    scan2_c<<<dim3(DI / DBLK, NCH, BATCH), blk, 0, stream>>>(delta, xcb, xdbl, A_log, D_param,
                                                             xzb, hfin, aprod, ybb);

    // 8. out_proj split-K(4) -> partials; fused reduce+resid+LN1 -> x1 + x1b
    gemm_sk<0, 4><<<dim3(12, 16, 4), blk, 0, stream>>>(ybb, wob, nullptr, nullptr, part_op,
                                                       NROWS, EMBED, DI, nullptr);
    reduce_ln<4, 0><<<NROWS, blk, 0, stream>>>(part_op, x, nullptr, ln1_w, ln1_b, x1, x1b);

    // 10. ffn1 + gelu -> fbf bf16
    gemm_sk<3, 1><<<dim3(48, 16, 1), blk, 0, stream>>>(x1b, wf1b, nullptr, fbf, nullptr,
                                                       NROWS, FF, EMBED, ffn_b1);

    // 11. ffn2 split-K(4) -> partials; fused reduce+bias+resid+LN2 -> out
    gemm_sk<0, 4><<<dim3(12, 16, 4), blk, 0, stream>>>(fbf, wf2b, nullptr, nullptr, part_f2,
                                                       NROWS, EMBED, FF, nullptr);
    reduce_ln<4, 1><<<NROWS, blk, 0, stream>>>(part_f2, x1, ffn_b2, ln2_w, ln2_b, out, nullptr);
}